// Round 1
// baseline (69038.885 us; speedup 1.0000x reference)
//
#include <hip/hip_runtime.h>
#include <stdint.h>
#include <stddef.h>

// ---------------------------------------------------------------------------
// Autoregressive decoder for MI355X (gfx950) — persistent mega-kernel.
// One kernel (k_run, 256 WGs x 256 thr, one WG/CU) runs all 400 steps with
// device-scope barriers. Per step, 5 phases:
//   A: GRU0 (input fused: WF = W_ih0@Wp so co feeds GRU0 directly)
//      + write mel/gate outputs of step t-1 (fp32) + zero ctx accumulators
//   B: GRU1 (gi1) + gh0' = h0@W_hh0^T (hoisted for next step)
//   C: gh1' = h1@W_hh1^T + u~ = h1@W_attn + c = h1.b_attn
//   D: attention over 512 enc steps; ctx/den reduced via f32 atomics
//   E: co = tanh([h1|ctx]@Wc^T + bc) -> co fp32 + bf16
// GEMVs via v_mfma_f32_16x16x32_bf16 (weights pre-rounded to bf16), fp32 acc.
// softmax w/o max-sub, clamped +-70 (identity in legit regime).
// State (h, gh, barrier counters) reset by in-graph prologue kernels each
// replay. No hipMalloc/sync in kernel_launch (graph-capture safe).
// ---------------------------------------------------------------------------

#define TM   400
#define NWG  256

typedef unsigned short ushort_t;
typedef short  short8  __attribute__((ext_vector_type(8)));
typedef float  float4v __attribute__((ext_vector_type(4)));

#define DEVI static __device__ __forceinline__

// swizzled-weight segment bases (in shorts, within g_sw)
#define SB_WF   0
#define SB_IH1  3145728
#define SB_HH0  6291456
#define SB_HH1  9437184
#define SB_AT   12582912
#define SB_WC   13631488
#define SW_TOT  15728640

__device__ __align__(16) ushort_t g_sw[SW_TOT];      // 31.5 MB bf16 weights
__device__ __align__(16) float    g_wf[3145728];     // WF = W_ih0 @ Wp (fp32)
__device__ __align__(16) ushort_t g_h0b[32768], g_h1b[32768];
__device__ __align__(16) float    g_h0f[32768], g_h1f[32768];
__device__ __align__(16) float    g_ubuf[32768], g_cbuf[32], g_b0f[3072];
__device__ __align__(16) float    g_gh0[98304], g_gh1[98304];
__device__ __align__(16) float    g_ctxn[32768], g_sden[32];   // atomic accums
__device__ __align__(16) float    g_cof[32768];      // co fp32
__device__ __align__(16) ushort_t g_cob[32768];      // co bf16
__device__ __align__(64) unsigned g_bar_cnt[16];     // [0] = arrival counter
__device__ __align__(64) unsigned g_bar_flag[128];   // 8 replicas @ stride 16

DEVI ushort_t f2b(float f) {                // float -> bf16 bits, RNE
  union { float f; uint32_t u; } c; c.f = f;
  uint32_t u = c.u + 0x7fffu + ((c.u >> 16) & 1u);
  return (ushort_t)(u >> 16);
}
DEVI float sigm(float x) { return 1.f / (1.f + __expf(-x)); }

DEVI float4v mfma16(short8 a, short8 b, float4v c) {
  return __builtin_amdgcn_mfma_f32_16x16x32_bf16(a, b, c, 0, 0, 0);
}

DEVI short8 frag_scale(const float* p, float s) {
  short8 r;
#pragma unroll
  for (int i = 0; i < 8; ++i) r[i] = (short)f2b(p[i] * s);
  return r;
}

// A: bf16 [32 x K] row-major; B: pre-swizzled frags. One 16x16 output tile.
DEVI float4v gemm_bf16(const ushort_t* Ab, int K, const ushort_t* Bw,
                       int ntile, int mu, int lane) {
  float4v acc = {0.f, 0.f, 0.f, 0.f};
  const int KB = K >> 5;
  const ushort_t* a = Ab + (size_t)(mu * 16 + (lane & 15)) * K + ((lane >> 4) << 3);
  const ushort_t* b = Bw + ((size_t)ntile * KB * 64 + lane) * 8;
  for (int kb = 0; kb < KB; ++kb) {
    short8 av = *(const short8*)(a + kb * 32);
    short8 bv = *(const short8*)(b + (size_t)kb * 512);
    acc = mfma16(av, bv, acc);
  }
  return acc;
}

// S4 gemm: A = [h1 bf16 (k<1024) | ctx*inv (k>=1024)], K = 2048
DEVI float4v gemm_s4(const ushort_t* h1b, const float* ctxn, const float* sden,
                     const ushort_t* Bw, int ntile, int mu, int lane) {
  float4v acc = {0.f, 0.f, 0.f, 0.f};
  const int m = mu * 16 + (lane & 15), ko = (lane >> 4) << 3;
  const ushort_t* a0 = h1b + m * 1024 + ko;
  const float* a1 = ctxn + m * 1024 + ko;
  const float den = sden[m];
  const float inv = (den > 1e-35f) ? (1.f / den) : 0.f;
  const ushort_t* b = Bw + ((size_t)ntile * 64 * 64 + lane) * 8;
  for (int kb = 0; kb < 32; ++kb)
    acc = mfma16(*(const short8*)(a0 + kb * 32), *(const short8*)(b + (size_t)kb * 512), acc);
  for (int kb = 32; kb < 64; ++kb) {
    short8 av = frag_scale(a1 + (kb - 32) * 32, inv);
    acc = mfma16(av, *(const short8*)(b + (size_t)kb * 512), acc);
  }
  return acc;
}

// scatter C-fragment into LDS: sh[q*256 + m*16 + n]
DEVI void put_tile(float* sh, int q, int lane, float4v a) {
  const int base = q * 256 + (lane & 15);
#pragma unroll
  for (int i = 0; i < 4; ++i) sh[base + ((lane >> 4) * 4 + i) * 16] = a[i];
}

// ---------------------------------------------------------------------------
// Device-scope barrier: monotonic epoch, single arrival counter, 8 replicated
// release flags (64B apart). __threadfence() provides release/writeback before
// arrival and acquire/invalidate after release — same coherence work a kernel
// boundary does. idx starts at 1 and increases monotonically (reset per replay
// by k_init).
// ---------------------------------------------------------------------------
DEVI void gbar(unsigned idx, int tid, int wg) {
  __syncthreads();
  if (tid == 0) {
    __threadfence();
    const unsigned old = __hip_atomic_fetch_add(&g_bar_cnt[0], 1u,
                           __ATOMIC_RELAXED, __HIP_MEMORY_SCOPE_AGENT);
    if (old == idx * NWG - 1u) {
#pragma unroll
      for (int r = 0; r < 8; ++r)
        __hip_atomic_store(&g_bar_flag[r * 16], idx,
                           __ATOMIC_RELAXED, __HIP_MEMORY_SCOPE_AGENT);
    } else {
      unsigned* fp = &g_bar_flag[(wg & 7) * 16];
      while (__hip_atomic_load(fp, __ATOMIC_RELAXED,
                               __HIP_MEMORY_SCOPE_AGENT) < idx)
        __builtin_amdgcn_s_sleep(4);
    }
    __threadfence();
  }
  __syncthreads();
}

// ---------------------------------------------------------------------------
// Prologue: WF = W_ih0 @ Wp  (fp32, [3072 x 1024])
// ---------------------------------------------------------------------------
__global__ void k_wf(const float* __restrict__ Wih0, const float* __restrict__ Wp) {
  __shared__ __align__(16) float As[32][128];
  __shared__ __align__(16) float Bs[128][64];
  const int tid = threadIdx.x;
  const int nt = blockIdx.x >> 4, kt = blockIdx.x & 15;
  const int n0 = nt * 32, k0 = kt * 64;
  {
    const int r = tid >> 3, c0 = (tid & 7) * 16;
    for (int i = 0; i < 16; i += 4)
      *(float4v*)&As[r][c0 + i] = *(const float4v*)&Wih0[(size_t)(n0 + r) * 128 + c0 + i];
  }
  {
    const int r = tid >> 1, c0 = (tid & 1) * 32;
    for (int i = 0; i < 32; i += 4)
      *(float4v*)&Bs[r][c0 + i] = *(const float4v*)&Wp[(size_t)r * 1024 + k0 + c0 + i];
  }
  __syncthreads();
  const int rn = tid >> 3, kq = (tid & 7) * 8;
  float acc[8] = {0.f, 0.f, 0.f, 0.f, 0.f, 0.f, 0.f, 0.f};
  for (int m = 0; m < 128; ++m) {
    const float a = As[rn][m];
#pragma unroll
    for (int j = 0; j < 8; ++j) acc[j] += a * Bs[m][kq + j];
  }
  float* dst = g_wf + (size_t)(n0 + rn) * 1024 + k0 + kq;
#pragma unroll
  for (int j = 0; j < 8; ++j) dst[j] = acc[j];
}

// ---------------------------------------------------------------------------
// Prologue: round fp32 weights to bf16 and repack into B-fragment order.
// lane L holds B[k = kb*32 + (L>>4)*8 + i][n = ntile*16 + (L&15)]
// ---------------------------------------------------------------------------
__global__ void k_swz(const float* __restrict__ W1, const float* __restrict__ W2,
                      const float* __restrict__ W3, const float* __restrict__ WA,
                      const float* __restrict__ WC) {
  long fid = (long)blockIdx.x * 256 + threadIdx.x;
  if (fid >= 1966080) return;
  const float* src; int N, K; long base, local; bool tr = false;
  if      (fid < 393216)  { src = g_wf; N = 3072; K = 1024; base = SB_WF;  local = fid; }
  else if (fid < 786432)  { src = W1;   N = 3072; K = 1024; base = SB_IH1; local = fid - 393216; }
  else if (fid < 1179648) { src = W2;   N = 3072; K = 1024; base = SB_HH0; local = fid - 786432; }
  else if (fid < 1572864) { src = W3;   N = 3072; K = 1024; base = SB_HH1; local = fid - 1179648; }
  else if (fid < 1703936) { src = WA;   N = 1024; K = 1024; base = SB_AT;  local = fid - 1572864; tr = true; }
  else                    { src = WC;   N = 1024; K = 2048; base = SB_WC;  local = fid - 1703936; }
  const int L = (int)(local & 63);
  long rest = local >> 6;
  const int KB = K >> 5;
  const int kb = (int)(rest % KB);
  const int nt = (int)(rest / KB);
  const int n  = nt * 16 + (L & 15);
  const int k0 = kb * 32 + ((L >> 4) << 3);
  short8 r;
#pragma unroll
  for (int i = 0; i < 8; ++i) {
    float f = tr ? src[(size_t)(k0 + i) * N + n] : src[(size_t)n * K + (k0 + i)];
    r[i] = (short)f2b(f);
  }
  *(short8*)(g_sw + base + local * 8) = r;
}

// Prologue: init states, mask output, fused bias b0f, barrier reset.
__global__ void k_init(const float* __restrict__ ehid, const int* __restrict__ lens,
                       const float* __restrict__ Wih0, const float* __restrict__ bp,
                       const float* __restrict__ bih0,
                       float* __restrict__ out, int out_size) {
  int i = blockIdx.x * 256 + threadIdx.x;
  if (i == 0) {
    g_bar_cnt[0] = 0u;
#pragma unroll
    for (int r = 0; r < 8; ++r) g_bar_flag[r * 16] = 0u;
  }
  if (i < 32768) { float v = ehid[i]; g_h0f[i] = v; g_h0b[i] = f2b(v); }
  else if (i < 65536) {
    int j = i - 32768; float v = ehid[32768 + j];
    g_h1f[j] = v; g_h1b[j] = f2b(v);
  } else if (i < 78336) {
    int mi = i - 65536; int b = mi / 400, tt = mi % 400;
    int idx = 1651200 + mi;
    if (idx < out_size) out[idx] = (tt > lens[b]) ? 1.0f : 0.0f;
  } else if (i < 81408) {
    int n = i - 78336;
    float s = bih0[n];
    const float* wr = Wih0 + (size_t)n * 128;
    for (int m = 0; m < 128; ++m) s += bp[m] * wr[m];
    g_b0f[n] = s;
  }
}

// Prologue: gh0/gh1 for step 0 (h_init @ W_hh^T + b_hh).
__global__ void k_pre(const float* __restrict__ b_hh0, const float* __restrict__ b_hh1) {
  const int wg = blockIdx.x, tid = threadIdx.x;
  const int lane = tid & 63, wv = tid >> 6;
  __shared__ __align__(16) float sh[1536];
  const int qa = (wv < 2) ? wv * 2 : wv + 2;
  const int qb = (wv < 2) ? wv * 2 + 1 : -1;
  const ushort_t* Ab = (wg < 64) ? g_h0b : g_h1b;
  const ushort_t* Bw = g_sw + ((wg < 64) ? SB_HH0 : SB_HH1);
  const float* bhh = (wg < 64) ? b_hh0 : b_hh1;
  float* ghb = (wg < 64) ? g_gh0 : g_gh1;
  const int w16 = wg & 63;
  { int g = qa >> 1, mu = qa & 1;
    put_tile(sh, qa, lane, gemm_bf16(Ab, 1024, Bw, g * 64 + w16, mu, lane)); }
  if (qb >= 0) { int g = qb >> 1, mu = qb & 1;
    put_tile(sh, qb, lane, gemm_bf16(Ab, 1024, Bw, g * 64 + w16, mu, lane)); }
  __syncthreads();
  const int jl = tid & 15, mr = tid >> 4, jg = w16 * 16 + jl;
#pragma unroll
  for (int mu = 0; mu < 2; ++mu) {
    const int b = mu * 16 + mr;
#pragma unroll
    for (int g = 0; g < 3; ++g)
      ghb[b * 3072 + g * 1024 + jg] = sh[(g * 2 + mu) * 256 + tid] + bhh[g * 1024 + jg];
  }
}

// ---------------------------------------------------------------------------
// Phase A: GRU0 (WGs 0..63, A = co bf16, B = WF) ; mel writers t-1 (64..127);
// gate writer t-1 (128); zero ctx/den accumulators (129..136).
// ---------------------------------------------------------------------------
DEVI void phaseA(int t, int wg, int tid,
                 const float* __restrict__ b_ih0, const float* __restrict__ bp,
                 const float* __restrict__ Wp, const float* __restrict__ Wg,
                 const float* __restrict__ bg, const int* __restrict__ lens,
                 float* __restrict__ out, int out_size, float* sh) {
  const int lane = tid & 63, wv = tid >> 6;
  if (wg < 64) {
    if (t >= TM) return;
    const int qa = (wv < 2) ? wv * 2 : wv + 2;
    const int qb = (wv < 2) ? wv * 2 + 1 : -1;
    const ushort_t* SW = g_sw + SB_WF;
    float4v acc;
    { int g = qa >> 1, mu = qa & 1;
      acc = (t > 0) ? gemm_bf16(g_cob, 1024, SW, g * 64 + wg, mu, lane)
                    : float4v{0.f, 0.f, 0.f, 0.f};
      put_tile(sh, qa, lane, acc); }
    if (qb >= 0) { int g = qb >> 1, mu = qb & 1;
      acc = (t > 0) ? gemm_bf16(g_cob, 1024, SW, g * 64 + wg, mu, lane)
                    : float4v{0.f, 0.f, 0.f, 0.f};
      put_tile(sh, qb, lane, acc); }
    __syncthreads();
    const int jl = tid & 15, mr = tid >> 4, jg = wg * 16 + jl;
    const float* bs = (t > 0) ? g_b0f : b_ih0;   // t=0: dec_in = 0 -> plain b_ih0
    const float bir = bs[jg], biz = bs[1024 + jg], bin = bs[2048 + jg];
#pragma unroll
    for (int mu = 0; mu < 2; ++mu) {
      const int b = mu * 16 + mr;
      float gr = sh[mu * 256 + tid]       + bir + g_gh0[b * 3072 + jg];
      float gz = sh[(2 + mu) * 256 + tid] + biz + g_gh0[b * 3072 + 1024 + jg];
      float gn = sh[(4 + mu) * 256 + tid] + bin;
      float r = sigm(gr), z = sigm(gz);
      float nn = tanhf(gn + r * g_gh0[b * 3072 + 2048 + jg]);
      float h = (1.f - z) * nn + z * g_h0f[b * 1024 + jg];
      g_h0f[b * 1024 + jg] = h; g_h0b[b * 1024 + jg] = f2b(h);
    }
  } else if (wg < 128) {
    if (t == 0) return;
    const int idx = wg - 64, b = idx & 31, mh = idx >> 5;
    const int m = mh * 64 + (tid >> 2), q = tid & 3;
    const float* cop = g_cof + b * 1024 + q * 256;
    const float* wpp = Wp + (size_t)m * 1024 + q * 256;
    float s = 0.f;
#pragma unroll 8
    for (int k = 0; k < 256; k += 4) {
      float4v cv = *(const float4v*)(cop + k);
      float4v wv4 = *(const float4v*)(wpp + k);
      s += cv[0] * wv4[0] + cv[1] * wv4[1] + cv[2] * wv4[2] + cv[3] * wv4[3];
    }
    s += __shfl_xor(s, 1, 64);
    s += __shfl_xor(s, 2, 64);
    if (q == 0) {
      const bool mk = (t - 1) > lens[b];
      const float v = mk ? 0.f : (s + bp[m]);
      const int oidx = b * 51200 + (t - 1) * 128 + m;
      if (oidx < out_size) out[oidx] = v;
    }
  } else if (wg == 128) {
    if (t == 0) return;
    const int b = tid >> 3, seg = tid & 7;
    const float* cop = g_cof + b * 1024 + seg * 128;
    const float* wgp = Wg + seg * 128;
    float s = 0.f;
#pragma unroll 8
    for (int k = 0; k < 128; k += 4) {
      float4v cv = *(const float4v*)(cop + k);
      float4v wv4 = *(const float4v*)(wgp + k);
      s += cv[0] * wv4[0] + cv[1] * wv4[1] + cv[2] * wv4[2] + cv[3] * wv4[3];
    }
    for (int off = 1; off < 8; off <<= 1) s += __shfl_xor(s, off, 64);
    if (seg == 0) {
      const bool mk = (t - 1) > lens[b];
      const float g = mk ? 1000.f : (s + bg[0]);
      const int oidx = 1638400 + b * 400 + (t - 1);
      if (oidx < out_size) out[oidx] = g;
    }
  } else if (wg >= 129 && wg < 137) {
    const int z = (wg - 129) * 256 + tid;
    float4v* c4 = (float4v*)g_ctxn;
    const float4v zv = {0.f, 0.f, 0.f, 0.f};
#pragma unroll
    for (int r = 0; r < 4; ++r) c4[z + r * 2048] = zv;
    if (wg == 129 && tid < 32) g_sden[tid] = 0.f;
  }
}

// Phase B: GRU1 gi1 + h1 update (WGs 0..63); gh0' for next step (64..127).
DEVI void phaseB(int wg, int tid, const float* __restrict__ b_ih1,
                 const float* __restrict__ b_hh0, float* sh) {
  const int lane = tid & 63, wv = tid >> 6;
  const int qa = (wv < 2) ? wv * 2 : wv + 2;
  const int qb = (wv < 2) ? wv * 2 + 1 : -1;
  if (wg < 64) {
    const ushort_t* SW = g_sw + SB_IH1;
    { int g = qa >> 1, mu = qa & 1;
      put_tile(sh, qa, lane, gemm_bf16(g_h0b, 1024, SW, g * 64 + wg, mu, lane)); }
    if (qb >= 0) { int g = qb >> 1, mu = qb & 1;
      put_tile(sh, qb, lane, gemm_bf16(g_h0b, 1024, SW, g * 64 + wg, mu, lane)); }
    __syncthreads();
    const int jl = tid & 15, mr = tid >> 4, jg = wg * 16 + jl;
    const float bir = b_ih1[jg], biz = b_ih1[1024 + jg], bin = b_ih1[2048 + jg];
#pragma unroll
    for (int mu = 0; mu < 2; ++mu) {
      const int b = mu * 16 + mr;
      float gr = sh[mu * 256 + tid]       + bir + g_gh1[b * 3072 + jg];
      float gz = sh[(2 + mu) * 256 + tid] + biz + g_gh1[b * 3072 + 1024 + jg];
      float gn = sh[(4 + mu) * 256 + tid] + bin;
      float r = sigm(gr), z = sigm(gz);
      float nn = tanhf(gn + r * g_gh1[b * 3072 + 2048 + jg]);
      float h = (1.f - z) * nn + z * g_h1f[b * 1024 + jg];
      g_h1f[b * 1024 + jg] = h; g_h1b[b * 1024 + jg] = f2b(h);
    }
  } else if (wg < 128) {
    const int w16 = wg - 64;
    const ushort_t* SW = g_sw + SB_HH0;
    { int g = qa >> 1, mu = qa & 1;
      put_tile(sh, qa, lane, gemm_bf16(g_h0b, 1024, SW, g * 64 + w16, mu, lane)); }
    if (qb >= 0) { int g = qb >> 1, mu = qb & 1;
      put_tile(sh, qb, lane, gemm_bf16(g_h0b, 1024, SW, g * 64 + w16, mu, lane)); }
    __syncthreads();
    const int jl = tid & 15, mr = tid >> 4, jg = w16 * 16 + jl;
#pragma unroll
    for (int mu = 0; mu < 2; ++mu) {
      const int b = mu * 16 + mr;
#pragma unroll
      for (int g = 0; g < 3; ++g)
        g_gh0[b * 3072 + g * 1024 + jg] = sh[(g * 2 + mu) * 256 + tid] + b_hh0[g * 1024 + jg];
    }
  }
}

// Phase C: gh1' for next step (WGs 0..63); u~ = h1@W_attn (64..127); c (128).
DEVI void phaseC(int wg, int tid, const float* __restrict__ b_hh1,
                 const float* __restrict__ b_attn, float* sh) {
  const int lane = tid & 63, wv = tid >> 6;
  if (wg < 64) {
    const int qa = (wv < 2) ? wv * 2 : wv + 2;
    const int qb = (wv < 2) ? wv * 2 + 1 : -1;
    const ushort_t* SW = g_sw + SB_HH1;
    { int g = qa >> 1, mu = qa & 1;
      put_tile(sh, qa, lane, gemm_bf16(g_h1b, 1024, SW, g * 64 + wg, mu, lane)); }
    if (qb >= 0) { int g = qb >> 1, mu = qb & 1;
      put_tile(sh, qb, lane, gemm_bf16(g_h1b, 1024, SW, g * 64 + wg, mu, lane)); }
    __syncthreads();
    const int jl = tid & 15, mr = tid >> 4, jg = wg * 16 + jl;
#pragma unroll
    for (int mu = 0; mu < 2; ++mu) {
      const int b = mu * 16 + mr;
#pragma unroll
      for (int g = 0; g < 3; ++g)
        g_gh1[b * 3072 + g * 1024 + jg] = sh[(g * 2 + mu) * 256 + tid] + b_hh1[g * 1024 + jg];
    }
  } else if (wg < 128) {
    const int nt = wg - 64;
    if (wv < 2) put_tile(sh, wv, lane, gemm_bf16(g_h1b, 1024, g_sw + SB_AT, nt, wv, lane));
    __syncthreads();
    const int nl = tid & 15, mr = tid >> 4, n = nt * 16 + nl;
    g_ubuf[mr * 1024 + n]        = sh[tid];
    g_ubuf[(16 + mr) * 1024 + n] = sh[256 + tid];
  } else if (wg == 128) {
    const int b = tid >> 3, seg = tid & 7;
    const float* hp = g_h1f + b * 1024 + seg * 128;
    const float* ba = b_attn + seg * 128;
    float s = 0.f;
    for (int k = 0; k < 128; ++k) s += hp[k] * ba[k];
    for (int off = 1; off < 8; off <<= 1) s += __shfl_xor(s, off, 64);
    if (seg == 0) g_cbuf[b] = s;
  }
}

// Phase D: attention. WG (b, slot): 64 enc timesteps; ctx/den via f32 atomics.
DEVI void phaseD(int wg, int tid, const float* __restrict__ enc, float* sh) {
  const int lane = tid & 63, wv = tid >> 6;
  const int b = wg >> 3, slot = wg & 7;
  const float* ub = g_ubuf + b * 1024;
  float4v u[4];
#pragma unroll
  for (int c = 0; c < 4; ++c) u[c] = *(const float4v*)(ub + c * 256 + lane * 4);
  const float cb = g_cbuf[b];
  float4v cx[4] = {{0.f,0.f,0.f,0.f},{0.f,0.f,0.f,0.f},{0.f,0.f,0.f,0.f},{0.f,0.f,0.f,0.f}};
  float sw = 0.f;
  const int t0 = slot * 64 + wv * 16;
  for (int it = 0; it < 16; ++it) {
    const float* encp = enc + ((size_t)(b * 512 + t0 + it) * 1024) + lane * 4;
    float4v e[4];
#pragma unroll
    for (int c = 0; c < 4; ++c) e[c] = *(const float4v*)(encp + c * 256);
    float s = 0.f;
#pragma unroll
    for (int c = 0; c < 4; ++c)
#pragma unroll
      for (int j = 0; j < 4; ++j) s += u[c][j] * e[c][j];
    for (int off = 1; off < 64; off <<= 1) s += __shfl_xor(s, off, 64);
    float sc = fminf(fmaxf(s + cb, -70.f), 70.f);   // identity in legit regime
    const float p = __expf(sc);
    sw += p;
#pragma unroll
    for (int c = 0; c < 4; ++c) cx[c] += p * e[c];
  }
#pragma unroll
  for (int c = 0; c < 4; ++c)
    *(float4v*)&sh[wv * 1024 + c * 256 + lane * 4] = cx[c];
  if (lane == 0) sh[4096 + wv] = sw;
  __syncthreads();
  float4v t4 = {0.f, 0.f, 0.f, 0.f};
#pragma unroll
  for (int vv = 0; vv < 4; ++vv) t4 += *(const float4v*)&sh[vv * 1024 + tid * 4];
  float* dst = g_ctxn + b * 1024 + tid * 4;
#pragma unroll
  for (int c = 0; c < 4; ++c) unsafeAtomicAdd(dst + c, t4[c]);
  if (tid == 0)
    unsafeAtomicAdd(&g_sden[b], sh[4096] + sh[4097] + sh[4098] + sh[4099]);
}

// Phase E: co = tanh([h1|ctx]@Wc^T + bc) -> g_cof (fp32) + g_cob (bf16).
DEVI void phaseE(int wg, int tid, const float* __restrict__ bc, float* sh) {
  if (wg >= 64) return;
  const int lane = tid & 63, wv = tid >> 6;
  if (wv < 2)
    put_tile(sh, wv, lane, gemm_s4(g_h1b, g_ctxn, g_sden, g_sw + SB_WC, wg, wv, lane));
  __syncthreads();
  const int jl = tid & 15, mr = tid >> 4;
  const float bcv = bc[wg * 16 + jl];
#pragma unroll
  for (int mu = 0; mu < 2; ++mu) {
    const int b = mu * 16 + mr;
    const float v = tanhf(sh[mu * 256 + tid] + bcv);
    g_cof[b * 1024 + wg * 16 + jl] = v;
    g_cob[b * 1024 + wg * 16 + jl] = f2b(v);
  }
}

// ---------------------------------------------------------------------------
// Persistent kernel: all 400 steps, 5 device-scope barriers per step.
// grid = 256 WGs x 256 thr (one per CU; co-resident by construction).
// ---------------------------------------------------------------------------
__global__ void __launch_bounds__(256) k_run(
    const float* __restrict__ enc,
    const float* __restrict__ b_ih0, const float* __restrict__ b_ih1,
    const float* __restrict__ b_hh0, const float* __restrict__ b_hh1,
    const float* __restrict__ b_attn, const float* __restrict__ bc,
    const float* __restrict__ Wp, const float* __restrict__ bp,
    const float* __restrict__ Wg, const float* __restrict__ bg,
    const int* __restrict__ lens, float* __restrict__ out, int out_size) {
  __shared__ __align__(16) float sh[4160];
  const int wg = blockIdx.x, tid = threadIdx.x;
  unsigned bar = 0;
  for (int t = 0; t < TM; ++t) {
    phaseA(t, wg, tid, b_ih0, bp, Wp, Wg, bg, lens, out, out_size, sh);
    gbar(++bar, tid, wg);
    phaseB(wg, tid, b_ih1, b_hh0, sh);
    gbar(++bar, tid, wg);
    phaseC(wg, tid, b_hh1, b_attn, sh);
    gbar(++bar, tid, wg);
    phaseD(wg, tid, enc, sh);
    gbar(++bar, tid, wg);
    phaseE(wg, tid, bc, sh);
    gbar(++bar, tid, wg);
  }
  // epilogue: outputs for t = TM-1 (writer roles only)
  phaseA(TM, wg, tid, b_ih0, bp, Wp, Wg, bg, lens, out, out_size, sh);
}

extern "C" void kernel_launch(void* const* d_in, const int* in_sizes, int n_in,
                              void* d_out, int out_size, void* d_ws, size_t ws_size,
                              hipStream_t stream) {
  const float* ehid  = (const float*)d_in[0];
  const float* enc   = (const float*)d_in[1];
  const int*   lens  = (const int*)d_in[3];
  const float* W_attn= (const float*)d_in[4];
  const float* b_attn= (const float*)d_in[5];
  const float* W_ih0 = (const float*)d_in[6];
  const float* W_hh0 = (const float*)d_in[7];
  const float* b_ih0 = (const float*)d_in[8];
  const float* b_hh0 = (const float*)d_in[9];
  const float* W_ih1 = (const float*)d_in[10];
  const float* W_hh1 = (const float*)d_in[11];
  const float* b_ih1 = (const float*)d_in[12];
  const float* b_hh1 = (const float*)d_in[13];
  const float* Wc    = (const float*)d_in[14];
  const float* bc    = (const float*)d_in[15];
  const float* Wp    = (const float*)d_in[16];
  const float* bp    = (const float*)d_in[17];
  const float* Wg    = (const float*)d_in[18];
  const float* bg    = (const float*)d_in[19];
  float* out = (float*)d_out;

  k_wf  <<<1536, 256, 0, stream>>>(W_ih0, Wp);
  k_swz <<<7680, 256, 0, stream>>>(W_ih1, W_hh0, W_hh1, W_attn, Wc);
  k_init<<<318, 256, 0, stream>>>(ehid, lens, W_ih0, bp, b_ih0, out, out_size);
  k_pre <<<128, 256, 0, stream>>>(b_hh0, b_hh1);
  k_run <<<NWG, 256, 0, stream>>>(enc, b_ih0, b_ih1, b_hh0, b_hh1, b_attn, bc,
                                  Wp, bp, Wg, bg, lens, out, out_size);
}

// Round 3
// 59752.094 us; speedup vs baseline: 1.1554x; 1.1554x over previous
//
#include <hip/hip_runtime.h>
#include <stdint.h>
#include <stddef.h>

// ---------------------------------------------------------------------------
// Autoregressive decoder for MI355X (gfx950) — persistent mega-kernel, v3.
// vs v2: zero inline asm (all LLC-routed traffic uses compiler-generated
// 8B SYSTEM-scope atomic loads/stores -> sc0 sc1, waitcnt-tracked), and the
// device barrier has a two-level arrival tree + bounded spin with a global
// dead-flag (a stuck barrier degrades to wrong-answer, never a hang).
// Cross-WG data is LLC-coherent by construction; weights/enc stay L2-hot.
// Per step, 5 phases (A..E) separated by flag barriers:
//   A: GRU0 (A-operand = co bf16 staged to LDS; B = WF = W_ih0@Wp)
//      + mel/gate output writers for t-1 + zero ctx accumulators
//   B: GRU1 (WGs 0..63) + gh0' = h0@W_hh0^T (64..127); A = h0b staged to LDS
//   C: gh1' (0..63) + u~ = h1@W_attn (64..127) + c-dot (128); A = h1b to LDS
//   D: attention over 512 enc steps; ctx/den reduced via f32 LLC atomics
//   E: co = tanh([h1|ctx]@Wc^T + bc); h1b reused from C's LDS copy,
//      ctx*inv staged to LDS as bf16
// ---------------------------------------------------------------------------

#define TM   400
#define NWG  256

typedef unsigned short ushort_t;
typedef unsigned long long u64_t;
typedef short    short8  __attribute__((ext_vector_type(8)));
typedef float    float4v __attribute__((ext_vector_type(4)));
typedef unsigned uint2v  __attribute__((ext_vector_type(2)));

#define DEVI static __device__ __forceinline__

// swizzled-weight segment bases (in shorts, within g_sw)
#define SB_WF   0
#define SB_IH1  3145728
#define SB_HH0  6291456
#define SB_HH1  9437184
#define SB_AT   12582912
#define SB_WC   13631488
#define SW_TOT  15728640

__device__ __align__(16) ushort_t g_sw[SW_TOT];      // bf16 weights (read-only, L2-cached)
__device__ __align__(16) float    g_wf[3145728];     // WF = W_ih0 @ Wp (fp32, prologue only)
__device__ __align__(16) ushort_t g_h0b[32768], g_h1b[32768];   // sc-only
__device__ __align__(16) float    g_h0f[32768];                 // WG-local, plain
__device__ __align__(16) float    g_h1f[32768];                 // sc-only
__device__ __align__(16) float    g_ubuf[32768], g_cbuf[32], g_b0f[3072];
__device__ __align__(16) float    g_gh0[98304];                 // sc-only
__device__ __align__(16) float    g_gh1[98304];                 // WG-local, plain
__device__ __align__(16) float    g_ctxn[32768], g_sden[32];    // LLC atomics
__device__ __align__(16) float    g_cof[32768];                 // sc-only
__device__ __align__(16) ushort_t g_cob[32768];                 // sc-only
__device__ __align__(64) unsigned g_bar_leaf[128];   // 8 leaves @ stride 16
__device__ __align__(64) unsigned g_bar_root[16];    // [0] = root counter
__device__ __align__(64) unsigned g_bar_flag[128];   // 8 replicas @ stride 16
__device__ __align__(64) unsigned g_bar_dead[16];    // [0] = timeout flag

DEVI ushort_t f2b(float f) {                // float -> bf16 bits, RNE
  union { float f; uint32_t u; } c; c.f = f;
  uint32_t u = c.u + 0x7fffu + ((c.u >> 16) & 1u);
  return (ushort_t)(u >> 16);
}
DEVI float sigm(float x) { return 1.f / (1.f + __expf(-x)); }

DEVI float4v mfma16(short8 a, short8 b, float4v c) {
  return __builtin_amdgcn_mfma_f32_16x16x32_bf16(a, b, c, 0, 0, 0);
}

// ---- coherent (LLC-routed) access helpers: compiler-generated sc0 sc1 -----
DEVI u64_t ld_sc8(const void* p) {
  return __hip_atomic_load((const u64_t*)p, __ATOMIC_RELAXED,
                           __HIP_MEMORY_SCOPE_SYSTEM);
}
DEVI float ld_scf(const float* p) {
  return __hip_atomic_load(p, __ATOMIC_RELAXED, __HIP_MEMORY_SCOPE_SYSTEM);
}
DEVI void st_scf(float* p, float v) {
  __hip_atomic_store(p, v, __ATOMIC_RELAXED, __HIP_MEMORY_SCOPE_SYSTEM);
}
DEVI void st_scu(unsigned* p, unsigned v) {
  __hip_atomic_store(p, v, __ATOMIC_RELAXED, __HIP_MEMORY_SCOPE_SYSTEM);
}

// stage a [32 x 1024] bf16 matrix (64KB) from global (via LLC) into LDS,
// XOR-swizzled so gemm_lds ds_read_b128 is ~conflict-free. 256 threads.
DEVI void stageA(const ushort_t* __restrict__ src, ushort_t* ldsA, int tid) {
#pragma unroll
  for (int half = 0; half < 2; ++half) {
    u64_t lo[8], hi[8];
#pragma unroll
    for (int j = 0; j < 8; ++j) {
      const int c = (half * 8 + j) * 256 + tid;       // 16B chunk id 0..4095
      lo[j] = ld_sc8(src + (size_t)c * 8);
      hi[j] = ld_sc8(src + (size_t)c * 8 + 4);
    }
#pragma unroll
    for (int j = 0; j < 8; ++j) {
      const int c = (half * 8 + j) * 256 + tid;
      const int r = c >> 7, s = c & 127;
      u64_t* dst = (u64_t*)((char*)ldsA + r * 2048 + ((s ^ (r & 7)) << 4));
      dst[0] = lo[j]; dst[1] = hi[j];
    }
  }
  __syncthreads();
}

// A from swizzled LDS [32][1024] bf16; B pre-swizzled global (L2-hot). K=1024.
DEVI float4v gemm_lds(const ushort_t* ldsA, const ushort_t* Bw,
                      int ntile, int mu, int lane) {
  float4v acc = {0.f, 0.f, 0.f, 0.f};
  const int r = mu * 16 + (lane & 15);
  const int ko = lane >> 4;
  const int rx = (r & 7) << 4;
  const char* ab = (const char*)ldsA + r * 2048;
  const ushort_t* b = Bw + ((size_t)ntile * 32 * 64 + lane) * 8;
  for (int kb = 0; kb < 32; ++kb) {
    const int off = ((kb * 4 + ko) << 4) ^ rx;
    short8 av = *(const short8*)(ab + off);
    acc = mfma16(av, *(const short8*)(b + (size_t)kb * 512), acc);
  }
  return acc;
}

// E gemm: K=2048, A = [h1b (LDS from phase C) | ctx*inv bf16 (LDS)]
DEVI float4v gemm_E(const ushort_t* ldsA, const ushort_t* ldsC,
                    const ushort_t* Bw, int ntile, int mu, int lane) {
  float4v acc = {0.f, 0.f, 0.f, 0.f};
  const int r = mu * 16 + (lane & 15), ko = lane >> 4;
  const int rx = (r & 7) << 4;
  const char* a0 = (const char*)ldsA + r * 2048;
  const char* a1 = (const char*)ldsC + r * 2048;
  const ushort_t* b = Bw + ((size_t)ntile * 64 * 64 + lane) * 8;
  for (int kb = 0; kb < 32; ++kb) {
    const int off = ((kb * 4 + ko) << 4) ^ rx;
    acc = mfma16(*(const short8*)(a0 + off), *(const short8*)(b + (size_t)kb * 512), acc);
  }
  for (int kb = 0; kb < 32; ++kb) {
    const int off = ((kb * 4 + ko) << 4) ^ rx;
    acc = mfma16(*(const short8*)(a1 + off), *(const short8*)(b + (size_t)(kb + 32) * 512), acc);
  }
  return acc;
}

// stage ctx*inv as bf16 into swizzled LDS [32][1024]. 256 threads.
DEVI void stage_ctx(ushort_t* ldsC, int tid) {
  const int r = tid >> 3, g8 = tid & 7;       // 8 threads per batch-row
  const float den = ld_scf(&g_sden[r]);
  const float inv = (den > 1e-35f) ? (1.f / den) : 0.f;
  const float* src = g_ctxn + r * 1024 + g8 * 128;
#pragma unroll
  for (int half = 0; half < 4; ++half) {
    u64_t ta[8], tb[8];
#pragma unroll
    for (int j = 0; j < 8; ++j) {
      ta[j] = ld_sc8(src + (half * 8 + j) * 4);
      tb[j] = ld_sc8(src + (half * 8 + j) * 4 + 2);
    }
#pragma unroll
    for (int j = 0; j < 8; ++j) {
      union { u64_t u; float f[2]; } ca, cb2;
      ca.u = ta[j]; cb2.u = tb[j];
      const int c = g8 * 128 + (half * 8 + j) * 4;    // short col
      const int s = c >> 3, o = (c & 7) * 2;
      uint2v u;
      u[0] = (unsigned)f2b(ca.f[0] * inv)  | ((unsigned)f2b(ca.f[1] * inv) << 16);
      u[1] = (unsigned)f2b(cb2.f[0] * inv) | ((unsigned)f2b(cb2.f[1] * inv) << 16);
      *(uint2v*)((char*)ldsC + r * 2048 + ((s ^ (r & 7)) << 4) + o) = u;
    }
  }
  __syncthreads();
}

// scatter C-fragment into LDS: sh[q*256 + m*16 + n]
DEVI void put_tile(float* sh, int q, int lane, float4v a) {
  const int base = q * 256 + (lane & 15);
#pragma unroll
  for (int i = 0; i < 4; ++i) sh[base + ((lane >> 4) * 4 + i) * 16] = a[i];
}

// ---------------------------------------------------------------------------
// Device barrier. No cache fences: all cross-WG data is LLC-routed, and
// __syncthreads() drains each wave's vmcnt before the arrival.
// Two-level arrival (8 leaves -> root), 8 replicated release flags,
// bounded spin with dead-flag fallback (degrades to wrong answer, not hang).
// ---------------------------------------------------------------------------
DEVI void gbar(unsigned idx, int tid, int wg) {
  __syncthreads();    // emits s_waitcnt vmcnt(0) lgkmcnt(0) per wave
  if (tid == 0) {
    if (__hip_atomic_load(&g_bar_dead[0], __ATOMIC_RELAXED,
                          __HIP_MEMORY_SCOPE_AGENT) == 0u) {
      const unsigned leaf = (unsigned)(wg & 7);
      const unsigned old = __hip_atomic_fetch_add(&g_bar_leaf[leaf * 16], 1u,
                             __ATOMIC_RELAXED, __HIP_MEMORY_SCOPE_AGENT);
      if (old == idx * 32u - 1u) {                   // last of this leaf
        const unsigned o2 = __hip_atomic_fetch_add(&g_bar_root[0], 1u,
                              __ATOMIC_RELAXED, __HIP_MEMORY_SCOPE_AGENT);
        if (o2 == idx * 8u - 1u) {                   // last leaf -> release
#pragma unroll
          for (int r = 0; r < 8; ++r)
            __hip_atomic_store(&g_bar_flag[r * 16], idx,
                               __ATOMIC_RELAXED, __HIP_MEMORY_SCOPE_AGENT);
        }
      }
      const unsigned* fp = &g_bar_flag[leaf * 16];
      unsigned spins = 0;
      while (__hip_atomic_load(fp, __ATOMIC_RELAXED,
                               __HIP_MEMORY_SCOPE_AGENT) < idx) {
        __builtin_amdgcn_s_sleep(8);
        if (++spins > (1u << 20)) {                  // ~0.2s -> declare dead
          __hip_atomic_store(&g_bar_dead[0], 1u,
                             __ATOMIC_RELAXED, __HIP_MEMORY_SCOPE_AGENT);
          break;
        }
      }
    }
  }
  __syncthreads();
}

// ---------------------------------------------------------------------------
// Prologue: WF = W_ih0 @ Wp  (fp32, [3072 x 1024])
// ---------------------------------------------------------------------------
__global__ void k_wf(const float* __restrict__ Wih0, const float* __restrict__ Wp) {
  __shared__ __align__(16) float As[32][128];
  __shared__ __align__(16) float Bs[128][64];
  const int tid = threadIdx.x;
  const int nt = blockIdx.x >> 4, kt = blockIdx.x & 15;
  const int n0 = nt * 32, k0 = kt * 64;
  {
    const int r = tid >> 3, c0 = (tid & 7) * 16;
    for (int i = 0; i < 16; i += 4)
      *(float4v*)&As[r][c0 + i] = *(const float4v*)&Wih0[(size_t)(n0 + r) * 128 + c0 + i];
  }
  {
    const int r = tid >> 1, c0 = (tid & 1) * 32;
    for (int i = 0; i < 32; i += 4)
      *(float4v*)&Bs[r][c0 + i] = *(const float4v*)&Wp[(size_t)r * 1024 + k0 + c0 + i];
  }
  __syncthreads();
  const int rn = tid >> 3, kq = (tid & 7) * 8;
  float acc[8] = {0.f, 0.f, 0.f, 0.f, 0.f, 0.f, 0.f, 0.f};
  for (int m = 0; m < 128; ++m) {
    const float a = As[rn][m];
#pragma unroll
    for (int j = 0; j < 8; ++j) acc[j] += a * Bs[m][kq + j];
  }
  float* dst = g_wf + (size_t)(n0 + rn) * 1024 + k0 + kq;
#pragma unroll
  for (int j = 0; j < 8; ++j) dst[j] = acc[j];
}

// ---------------------------------------------------------------------------
// Prologue: round fp32 weights to bf16 and repack into B-fragment order.
// lane L holds B[k = kb*32 + (L>>4)*8 + i][n = ntile*16 + (L&15)]
// ---------------------------------------------------------------------------
__global__ void k_swz(const float* __restrict__ W1, const float* __restrict__ W2,
                      const float* __restrict__ W3, const float* __restrict__ WA,
                      const float* __restrict__ WC) {
  long fid = (long)blockIdx.x * 256 + threadIdx.x;
  if (fid >= 1966080) return;
  const float* src; int N, K; long base, local; bool tr = false;
  if      (fid < 393216)  { src = g_wf; N = 3072; K = 1024; base = SB_WF;  local = fid; }
  else if (fid < 786432)  { src = W1;   N = 3072; K = 1024; base = SB_IH1; local = fid - 393216; }
  else if (fid < 1179648) { src = W2;   N = 3072; K = 1024; base = SB_HH0; local = fid - 786432; }
  else if (fid < 1572864) { src = W3;   N = 3072; K = 1024; base = SB_HH1; local = fid - 1179648; }
  else if (fid < 1703936) { src = WA;   N = 1024; K = 1024; base = SB_AT;  local = fid - 1572864; tr = true; }
  else                    { src = WC;   N = 1024; K = 2048; base = SB_WC;  local = fid - 1703936; }
  const int L = (int)(local & 63);
  long rest = local >> 6;
  const int KB = K >> 5;
  const int kb = (int)(rest % KB);
  const int nt = (int)(rest / KB);
  const int n  = nt * 16 + (L & 15);
  const int k0 = kb * 32 + ((L >> 4) << 3);
  short8 r;
#pragma unroll
  for (int i = 0; i < 8; ++i) {
    float f = tr ? src[(size_t)(k0 + i) * N + n] : src[(size_t)n * K + (k0 + i)];
    r[i] = (short)f2b(f);
  }
  *(short8*)(g_sw + base + local * 8) = r;
}

// Prologue: init states, mask output, fused bias b0f, barrier reset.
__global__ void k_init(const float* __restrict__ ehid, const int* __restrict__ lens,
                       const float* __restrict__ Wih0, const float* __restrict__ bp,
                       const float* __restrict__ bih0,
                       float* __restrict__ out, int out_size) {
  int i = blockIdx.x * 256 + threadIdx.x;
  if (i == 0) {
#pragma unroll
    for (int r = 0; r < 8; ++r) {
      g_bar_leaf[r * 16] = 0u;
      g_bar_flag[r * 16] = 0u;
    }
    g_bar_root[0] = 0u;
    g_bar_dead[0] = 0u;
  }
  if (i < 32768) { float v = ehid[i]; g_h0f[i] = v; g_h0b[i] = f2b(v); }
  else if (i < 65536) {
    int j = i - 32768; float v = ehid[32768 + j];
    g_h1f[j] = v; g_h1b[j] = f2b(v);
  } else if (i < 78336) {
    int mi = i - 65536; int b = mi / 400, tt = mi % 400;
    int idx = 1651200 + mi;
    if (idx < out_size) out[idx] = (tt > lens[b]) ? 1.0f : 0.0f;
  } else if (i < 81408) {
    int n = i - 78336;
    float s = bih0[n];
    const float* wr = Wih0 + (size_t)n * 128;
    for (int m = 0; m < 128; ++m) s += bp[m] * wr[m];
    g_b0f[n] = s;
  }
}

// Prologue: gh0/gh1 for step 0 (h_init @ W_hh^T + b_hh). Plain accesses —
// kernel boundaries flush L2 so k_run's sc reads see fresh LLC data.
DEVI float4v gemm_plain(const ushort_t* Ab, const ushort_t* Bw,
                        int ntile, int mu, int lane) {
  float4v acc = {0.f, 0.f, 0.f, 0.f};
  const ushort_t* a = Ab + (size_t)(mu * 16 + (lane & 15)) * 1024 + ((lane >> 4) << 3);
  const ushort_t* b = Bw + ((size_t)ntile * 32 * 64 + lane) * 8;
  for (int kb = 0; kb < 32; ++kb) {
    short8 av = *(const short8*)(a + kb * 32);
    acc = mfma16(av, *(const short8*)(b + (size_t)kb * 512), acc);
  }
  return acc;
}

__global__ void k_pre(const float* __restrict__ b_hh0, const float* __restrict__ b_hh1) {
  const int wg = blockIdx.x, tid = threadIdx.x;
  const int lane = tid & 63, wv = tid >> 6;
  __shared__ __align__(16) float sh[1536];
  const int qa = (wv < 2) ? wv * 2 : wv + 2;
  const int qb = (wv < 2) ? wv * 2 + 1 : -1;
  const ushort_t* Ab = (wg < 64) ? g_h0b : g_h1b;
  const ushort_t* Bw = g_sw + ((wg < 64) ? SB_HH0 : SB_HH1);
  const float* bhh = (wg < 64) ? b_hh0 : b_hh1;
  float* ghb = (wg < 64) ? g_gh0 : g_gh1;
  const int w16 = wg & 63;
  { int g = qa >> 1, mu = qa & 1;
    put_tile(sh, qa, lane, gemm_plain(Ab, Bw, g * 64 + w16, mu, lane)); }
  if (qb >= 0) { int g = qb >> 1, mu = qb & 1;
    put_tile(sh, qb, lane, gemm_plain(Ab, Bw, g * 64 + w16, mu, lane)); }
  __syncthreads();
  const int jl = tid & 15, mr = tid >> 4, jg = w16 * 16 + jl;
#pragma unroll
  for (int mu = 0; mu < 2; ++mu) {
    const int b = mu * 16 + mr;
#pragma unroll
    for (int g = 0; g < 3; ++g)
      ghb[b * 3072 + g * 1024 + jg] = sh[(g * 2 + mu) * 256 + tid] + bhh[g * 1024 + jg];
  }
}

// ---------------------------------------------------------------------------
// Phase A: GRU0 (WGs 0..63); mel writers t-1 (64..127); gate writer (128);
// zero ctx/den accumulators (129..136).
// ---------------------------------------------------------------------------
DEVI void phaseA(int t, int wg, int tid,
                 const float* __restrict__ b_ih0, const float* __restrict__ bp,
                 const float* __restrict__ Wp, const float* __restrict__ Wg,
                 const float* __restrict__ bg, const int* __restrict__ lens,
                 float* __restrict__ out, int out_size,
                 ushort_t* ldsA, float* sh) {
  const int lane = tid & 63, wv = tid >> 6;
  if (wg < 64) {
    if (t >= TM) return;
    if (t > 0) stageA(g_cob, ldsA, tid);
    const int qa = (wv < 2) ? wv * 2 : wv + 2;
    const int qb = (wv < 2) ? wv * 2 + 1 : -1;
    const ushort_t* SW = g_sw + SB_WF;
    float4v acc;
    { int g = qa >> 1, mu = qa & 1;
      acc = (t > 0) ? gemm_lds(ldsA, SW, g * 64 + wg, mu, lane)
                    : float4v{0.f, 0.f, 0.f, 0.f};
      put_tile(sh, qa, lane, acc); }
    if (qb >= 0) { int g = qb >> 1, mu = qb & 1;
      acc = (t > 0) ? gemm_lds(ldsA, SW, g * 64 + wg, mu, lane)
                    : float4v{0.f, 0.f, 0.f, 0.f};
      put_tile(sh, qb, lane, acc); }
    __syncthreads();
    const int jl = tid & 15, mr = tid >> 4, jg = wg * 16 + jl;
    const float* bs = (t > 0) ? g_b0f : b_ih0;   // t=0: dec_in = 0 -> plain b_ih0
    const float bir = bs[jg], biz = bs[1024 + jg], bin = bs[2048 + jg];
#pragma unroll
    for (int mu = 0; mu < 2; ++mu) {
      const int b = mu * 16 + mr;
      const float g0 = ld_scf(&g_gh0[b * 3072 + jg]);
      const float g1 = ld_scf(&g_gh0[b * 3072 + 1024 + jg]);
      const float g2 = ld_scf(&g_gh0[b * 3072 + 2048 + jg]);
      float gr = sh[mu * 256 + tid]       + bir + g0;
      float gz = sh[(2 + mu) * 256 + tid] + biz + g1;
      float gn = sh[(4 + mu) * 256 + tid] + bin;
      float r = sigm(gr), z = sigm(gz);
      float nn = tanhf(gn + r * g2);
      float h = (1.f - z) * nn + z * g_h0f[b * 1024 + jg];
      g_h0f[b * 1024 + jg] = h;                       // WG-local, plain
      ushort_t hb = f2b(h);
      ushort_t hb1 = (ushort_t)__shfl_down((int)hb, 1, 64);
      if (!(jl & 1))
        st_scu((unsigned*)&g_h0b[b * 1024 + jg],
               (unsigned)hb | ((unsigned)hb1 << 16));
    }
  } else if (wg < 128) {
    if (t == 0) return;
    const int idx = wg - 64, b = idx & 31, mh = idx >> 5;
    { union { u64_t u; float f[2]; } a, b2;
      a.u  = ld_sc8(g_cof + b * 1024 + tid * 4);
      b2.u = ld_sc8(g_cof + b * 1024 + tid * 4 + 2);
      sh[tid * 4]     = a.f[0];  sh[tid * 4 + 1] = a.f[1];
      sh[tid * 4 + 2] = b2.f[0]; sh[tid * 4 + 3] = b2.f[1]; }
    __syncthreads();
    const int m = mh * 64 + (tid >> 2), q = tid & 3;
    const float* cop = sh + q * 256;
    const float* wpp = Wp + (size_t)m * 1024 + q * 256;
    float s = 0.f;
#pragma unroll 8
    for (int k = 0; k < 256; k += 4) {
      float4v cv = *(const float4v*)(cop + k);
      float4v wv4 = *(const float4v*)(wpp + k);
      s += cv[0] * wv4[0] + cv[1] * wv4[1] + cv[2] * wv4[2] + cv[3] * wv4[3];
    }
    s += __shfl_xor(s, 1, 64);
    s += __shfl_xor(s, 2, 64);
    if (q == 0) {
      const bool mk = (t - 1) > lens[b];
      const float v = mk ? 0.f : (s + bp[m]);
      const int oidx = b * 51200 + (t - 1) * 128 + m;
      if (oidx < out_size) out[oidx] = v;
    }
  } else if (wg == 128) {
    if (t == 0) return;
    const int b = tid >> 3, seg = tid & 7;
    const float* cop = g_cof + b * 1024 + seg * 128;
    const float* wgp = Wg + seg * 128;
    float s = 0.f;
#pragma unroll
    for (int j = 0; j < 64; ++j) {
      union { u64_t u; float f[2]; } cv; cv.u = ld_sc8(cop + j * 2);
      s += cv.f[0] * wgp[j * 2] + cv.f[1] * wgp[j * 2 + 1];
    }
    for (int off = 1; off < 8; off <<= 1) s += __shfl_xor(s, off, 64);
    if (seg == 0) {
      const bool mk = (t - 1) > lens[b];
      const float g = mk ? 1000.f : (s + bg[0]);
      const int oidx = 1638400 + b * 400 + (t - 1);
      if (oidx < out_size) out[oidx] = g;
    }
  } else if (wg >= 129 && wg < 137) {
    const int z0 = (wg - 129) * 256 + tid;    // 2048 threads over 32768 floats
#pragma unroll
    for (int r4 = 0; r4 < 16; ++r4)
      st_scf(&g_ctxn[z0 + r4 * 2048], 0.f);
    if (wg == 129 && tid < 32) st_scf(&g_sden[tid], 0.f);
  }
}

// Phase B: GRU1 (WGs 0..63); gh0' for next step (64..127). A = h0b.
DEVI void phaseB(int wg, int tid, const float* __restrict__ b_ih1,
                 const float* __restrict__ b_hh0, ushort_t* ldsA, float* sh) {
  if (wg >= 128) return;
  const int lane = tid & 63, wv = tid >> 6;
  stageA(g_h0b, ldsA, tid);
  const int qa = (wv < 2) ? wv * 2 : wv + 2;
  const int qb = (wv < 2) ? wv * 2 + 1 : -1;
  const bool lo = (wg < 64);
  const int w16 = wg & 63;
  const ushort_t* SW = g_sw + (lo ? SB_IH1 : SB_HH0);
  { int g = qa >> 1, mu = qa & 1;
    put_tile(sh, qa, lane, gemm_lds(ldsA, SW, g * 64 + w16, mu, lane)); }
  if (qb >= 0) { int g = qb >> 1, mu = qb & 1;
    put_tile(sh, qb, lane, gemm_lds(ldsA, SW, g * 64 + w16, mu, lane)); }
  __syncthreads();
  const int jl = tid & 15, mr = tid >> 4, jg = w16 * 16 + jl;
  if (lo) {
    const float bir = b_ih1[jg], biz = b_ih1[1024 + jg], bin = b_ih1[2048 + jg];
#pragma unroll
    for (int mu = 0; mu < 2; ++mu) {
      const int b = mu * 16 + mr;
      float gr = sh[mu * 256 + tid]       + bir + g_gh1[b * 3072 + jg];
      float gz = sh[(2 + mu) * 256 + tid] + biz + g_gh1[b * 3072 + 1024 + jg];
      float gn = sh[(4 + mu) * 256 + tid] + bin;
      float r = sigm(gr), z = sigm(gz);
      float nn = tanhf(gn + r * g_gh1[b * 3072 + 2048 + jg]);
      const float hold = ld_scf(&g_h1f[b * 1024 + jg]);
      float h = (1.f - z) * nn + z * hold;
      st_scf(&g_h1f[b * 1024 + jg], h);
      ushort_t hb = f2b(h);
      ushort_t hb1 = (ushort_t)__shfl_down((int)hb, 1, 64);
      if (!(jl & 1))
        st_scu((unsigned*)&g_h1b[b * 1024 + jg],
               (unsigned)hb | ((unsigned)hb1 << 16));
    }
  } else {
#pragma unroll
    for (int mu = 0; mu < 2; ++mu) {
      const int b = mu * 16 + mr;
#pragma unroll
      for (int g = 0; g < 3; ++g)
        st_scf(&g_gh0[b * 3072 + g * 1024 + jg],
               sh[(g * 2 + mu) * 256 + tid] + b_hh0[g * 1024 + jg]);
    }
  }
}

// Phase C: gh1' (WGs 0..63, plain: WG-local); u~ (64..127); c-dot (128). A = h1b.
DEVI void phaseC(int wg, int tid, const float* __restrict__ b_hh1,
                 const float* __restrict__ b_attn, ushort_t* ldsA, float* sh) {
  const int lane = tid & 63, wv = tid >> 6;
  if (wg < 128) {
    stageA(g_h1b, ldsA, tid);
    if (wg < 64) {
      const int qa = (wv < 2) ? wv * 2 : wv + 2;
      const int qb = (wv < 2) ? wv * 2 + 1 : -1;
      const ushort_t* SW = g_sw + SB_HH1;
      { int g = qa >> 1, mu = qa & 1;
        put_tile(sh, qa, lane, gemm_lds(ldsA, SW, g * 64 + wg, mu, lane)); }
      if (qb >= 0) { int g = qb >> 1, mu = qb & 1;
        put_tile(sh, qb, lane, gemm_lds(ldsA, SW, g * 64 + wg, mu, lane)); }
      __syncthreads();
      const int jl = tid & 15, mr = tid >> 4, jg = wg * 16 + jl;
#pragma unroll
      for (int mu = 0; mu < 2; ++mu) {
        const int b = mu * 16 + mr;
#pragma unroll
        for (int g = 0; g < 3; ++g)
          g_gh1[b * 3072 + g * 1024 + jg] = sh[(g * 2 + mu) * 256 + tid] + b_hh1[g * 1024 + jg];
      }
    } else {
      const int nt = wg - 64;
      if (wv < 2) put_tile(sh, wv, lane, gemm_lds(ldsA, g_sw + SB_AT, nt, wv, lane));
      __syncthreads();
      const int nl = tid & 15, mr = tid >> 4, n = nt * 16 + nl;
      st_scf(&g_ubuf[mr * 1024 + n],        sh[tid]);
      st_scf(&g_ubuf[(16 + mr) * 1024 + n], sh[256 + tid]);
    }
  } else if (wg == 128) {
    const int b = tid >> 3, seg = tid & 7;
    const float* hp = g_h1f + b * 1024 + seg * 128;
    const float* ba = b_attn + seg * 128;
    float s = 0.f;
#pragma unroll
    for (int j = 0; j < 64; ++j) {
      union { u64_t u; float f[2]; } hv; hv.u = ld_sc8(hp + j * 2);
      s += hv.f[0] * ba[j * 2] + hv.f[1] * ba[j * 2 + 1];
    }
    for (int off = 1; off < 8; off <<= 1) s += __shfl_xor(s, off, 64);
    if (seg == 0) st_scf(&g_cbuf[b], s);
  }
}

// Phase D: attention. WG (b, slot): 64 enc timesteps; ctx/den via f32 atomics.
DEVI void phaseD(int wg, int tid, const float* __restrict__ enc, float* sh) {
  const int lane = tid & 63, wv = tid >> 6;
  const int b = wg >> 3, slot = wg & 7;
  const float* ub = g_ubuf + b * 1024;
  float4v u[4];
#pragma unroll
  for (int c = 0; c < 4; ++c) {
    union { u64_t u; float f[2]; } a, b2;
    a.u  = ld_sc8(ub + c * 256 + lane * 4);
    b2.u = ld_sc8(ub + c * 256 + lane * 4 + 2);
    u[c][0] = a.f[0]; u[c][1] = a.f[1]; u[c][2] = b2.f[0]; u[c][3] = b2.f[1];
  }
  const float cb = ld_scf(&g_cbuf[b]);
  float4v cx[4] = {{0.f,0.f,0.f,0.f},{0.f,0.f,0.f,0.f},{0.f,0.f,0.f,0.f},{0.f,0.f,0.f,0.f}};
  float sw = 0.f;
  const int t0 = slot * 64 + wv * 16;
  for (int it = 0; it < 16; ++it) {
    const float* encp = enc + ((size_t)(b * 512 + t0 + it) * 1024) + lane * 4;
    float4v e[4];
#pragma unroll
    for (int c = 0; c < 4; ++c) e[c] = *(const float4v*)(encp + c * 256);
    float s = 0.f;
#pragma unroll
    for (int c = 0; c < 4; ++c)
#pragma unroll
      for (int j = 0; j < 4; ++j) s += u[c][j] * e[c][j];
    for (int off = 1; off < 64; off <<= 1) s += __shfl_xor(s, off, 64);
    float sc = fminf(fmaxf(s + cb, -70.f), 70.f);   // identity in legit regime
    const float p = __expf(sc);
    sw += p;
#pragma unroll
    for (int c = 0; c < 4; ++c) cx[c] += p * e[c];
  }
#pragma unroll
  for (int c = 0; c < 4; ++c)
    *(float4v*)&sh[wv * 1024 + c * 256 + lane * 4] = cx[c];
  if (lane == 0) sh[4096 + wv] = sw;
  __syncthreads();
  float4v t4 = {0.f, 0.f, 0.f, 0.f};
#pragma unroll
  for (int vv = 0; vv < 4; ++vv) t4 += *(const float4v*)&sh[vv * 1024 + tid * 4];
  float* dst = g_ctxn + b * 1024 + tid * 4;
#pragma unroll
  for (int c = 0; c < 4; ++c) unsafeAtomicAdd(dst + c, t4[c]);
  if (tid == 0)
    unsafeAtomicAdd(&g_sden[b], sh[4096] + sh[4097] + sh[4098] + sh[4099]);
}

// Phase E: co = tanh([h1|ctx]@Wc^T + bc) -> g_cof (fp32) + g_cob (bf16).
// h1b reused from phase C's LDS copy; ctx*inv staged as bf16 to ldsC.
DEVI void phaseE(int wg, int tid, const float* __restrict__ bc,
                 ushort_t* ldsA, ushort_t* ldsC, float* sh) {
  if (wg >= 64) return;
  const int lane = tid & 63, wv = tid >> 6;
  stage_ctx(ldsC, tid);
  if (wv < 2)
    put_tile(sh, wv, lane, gemm_E(ldsA, ldsC, g_sw + SB_WC, wg, wv, lane));
  __syncthreads();
  const int jl = tid & 15, mr = tid >> 4;
  const float bcv = bc[wg * 16 + jl];
#pragma unroll
  for (int mu = 0; mu < 2; ++mu) {
    const int b = mu * 16 + mr;
    const float v = tanhf(sh[mu * 256 + tid] + bcv);
    st_scf(&g_cof[b * 1024 + wg * 16 + jl], v);
    ushort_t hb = f2b(v);
    ushort_t hb1 = (ushort_t)__shfl_down((int)hb, 1, 64);
    if (!(jl & 1))
      st_scu((unsigned*)&g_cob[b * 1024 + wg * 16 + jl],
             (unsigned)hb | ((unsigned)hb1 << 16));
  }
}

// ---------------------------------------------------------------------------
// Persistent kernel: all 400 steps, 5 device-scope barriers per step.
// grid = 256 WGs x 256 thr (one per CU; co-resident by construction).
// ---------------------------------------------------------------------------
__global__ void __launch_bounds__(256) k_run(
    const float* __restrict__ enc,
    const float* __restrict__ b_ih0, const float* __restrict__ b_ih1,
    const float* __restrict__ b_hh0, const float* __restrict__ b_hh1,
    const float* __restrict__ b_attn, const float* __restrict__ bc,
    const float* __restrict__ Wp, const float* __restrict__ bp,
    const float* __restrict__ Wg, const float* __restrict__ bg,
    const int* __restrict__ lens, float* __restrict__ out, int out_size) {
  __shared__ __align__(16) ushort_t ldsA[32 * 1024];   // 64 KB staged A
  __shared__ __align__(16) ushort_t ldsC[32 * 1024];   // 64 KB staged ctx
  __shared__ __align__(16) float sh[4160];             // 16.6 KB tiles/partials
  const int wg = blockIdx.x, tid = threadIdx.x;
  unsigned bar = 0;
  for (int t = 0; t < TM; ++t) {
    phaseA(t, wg, tid, b_ih0, bp, Wp, Wg, bg, lens, out, out_size, ldsA, sh);
    gbar(++bar, tid, wg);
    phaseB(wg, tid, b_ih1, b_hh0, ldsA, sh);
    gbar(++bar, tid, wg);
    phaseC(wg, tid, b_hh1, b_attn, ldsA, sh);
    gbar(++bar, tid, wg);
    phaseD(wg, tid, enc, sh);
    gbar(++bar, tid, wg);
    phaseE(wg, tid, bc, ldsA, ldsC, sh);
    gbar(++bar, tid, wg);
  }
  // epilogue: outputs for t = TM-1 (writer roles only)
  phaseA(TM, wg, tid, b_ih0, bp, Wp, Wg, bg, lens, out, out_size, ldsA, sh);
}

extern "C" void kernel_launch(void* const* d_in, const int* in_sizes, int n_in,
                              void* d_out, int out_size, void* d_ws, size_t ws_size,
                              hipStream_t stream) {
  const float* ehid  = (const float*)d_in[0];
  const float* enc   = (const float*)d_in[1];
  const int*   lens  = (const int*)d_in[3];
  const float* W_attn= (const float*)d_in[4];
  const float* b_attn= (const float*)d_in[5];
  const float* W_ih0 = (const float*)d_in[6];
  const float* W_hh0 = (const float*)d_in[7];
  const float* b_ih0 = (const float*)d_in[8];
  const float* b_hh0 = (const float*)d_in[9];
  const float* W_ih1 = (const float*)d_in[10];
  const float* W_hh1 = (const float*)d_in[11];
  const float* b_ih1 = (const float*)d_in[12];
  const float* b_hh1 = (const float*)d_in[13];
  const float* Wc    = (const float*)d_in[14];
  const float* bc    = (const float*)d_in[15];
  const float* Wp    = (const float*)d_in[16];
  const float* bp    = (const float*)d_in[17];
  const float* Wg    = (const float*)d_in[18];
  const float* bg    = (const float*)d_in[19];
  float* out = (float*)d_out;

  k_wf  <<<1536, 256, 0, stream>>>(W_ih0, Wp);
  k_swz <<<7680, 256, 0, stream>>>(W_ih1, W_hh0, W_hh1, W_attn, Wc);
  k_init<<<318, 256, 0, stream>>>(ehid, lens, W_ih0, bp, b_ih0, out, out_size);
  k_pre <<<128, 256, 0, stream>>>(b_hh0, b_hh1);
  k_run <<<NWG, 256, 0, stream>>>(enc, b_ih0, b_ih1, b_hh0, b_hh1, b_attn, bc,
                                  Wp, bp, Wg, bg, lens, out, out_size);
}

// Round 5
// 51156.042 us; speedup vs baseline: 1.3496x; 1.1680x over previous
//
#include <hip/hip_runtime.h>
#include <stdint.h>
#include <stddef.h>

// ---------------------------------------------------------------------------
// Autoregressive decoder for MI355X (gfx950) — persistent mega-kernel, v5.
// v4 with one bug fixed: the ldsE enc-slice fill loop only initialized 1/4
// of the 128 KB buffer (16B loads at 64B stride); phase D read uninitialized
// LDS -> NaN. Now 32 iterations x 16B stride = full 128 KB, + syncthreads.
// Design (validated pieces from v1/v3):
//   - enc bf16 parked in LDS once (128 KB/WG, 32 MB chip-wide); phase D runs
//     entirely from LDS -> kills the 26 GB/dispatch enc re-fetch of v1/v3.
//   - GEMV A-operands via direct chunked LLC (sc0 sc1) fragment loads.
//   - Cross-WG exchange exclusively via SYSTEM-scope atomic ld/st (LLC
//     coherent); weights/enc-bf16 plain loads (L2-hot).
//   - Barrier: two-level arrival tree + bounded spin + dead-flag, no fences.
// Per step, 5 phases:
//   A: GRU0 (A = co bf16, B = WF = W_ih0@Wp) + mel/gate writers (t-1)
//      + zero ctx accumulators
//   B: GRU1 (WGs 0..63) + gh0' = h0@W_hh0^T (64..127)
//   C: gh1' (0..63) + u~ = h1@W_attn (64..127) + c-dot (128)
//   D: attention from LDS enc; ctx/den reduced via f32 LLC atomics
//   E: co = tanh([h1|ctx]@Wc^T + bc) (h1 bf16 sc + ctx*inv on the fly)
// ---------------------------------------------------------------------------

#define TM   400
#define NWG  256

typedef unsigned short ushort_t;
typedef unsigned long long u64_t;
typedef short    short8  __attribute__((ext_vector_type(8)));
typedef float    float4v __attribute__((ext_vector_type(4)));

#define DEVI static __device__ __forceinline__

// swizzled-weight segment bases (in shorts, within g_sw)
#define SB_WF   0
#define SB_IH1  3145728
#define SB_HH0  6291456
#define SB_HH1  9437184
#define SB_AT   12582912
#define SB_WC   13631488
#define SW_TOT  15728640

__device__ __align__(16) ushort_t g_sw[SW_TOT];      // bf16 weights (L2-hot)
__device__ __align__(16) float    g_wf[3145728];     // WF = W_ih0 @ Wp (prologue)
__device__ __align__(16) ushort_t g_encb[16777216];  // enc bf16 [32][512][1024]
__device__ __align__(16) ushort_t g_h0b[32768], g_h1b[32768];   // sc-only
__device__ __align__(16) float    g_h0f[32768];                 // WG-local, plain
__device__ __align__(16) float    g_h1f[32768];                 // sc-only
__device__ __align__(16) float    g_ubuf[32768], g_cbuf[32], g_b0f[3072];
__device__ __align__(16) float    g_gh0[98304];                 // sc-only
__device__ __align__(16) float    g_gh1[98304];                 // WG-local, plain
__device__ __align__(16) float    g_ctxn[32768], g_sden[32];    // LLC atomics
__device__ __align__(16) float    g_cof[32768];                 // sc-only
__device__ __align__(16) ushort_t g_cob[32768];                 // sc-only
__device__ __align__(64) unsigned g_bar_leaf[128];   // 8 leaves @ stride 16
__device__ __align__(64) unsigned g_bar_root[16];    // [0] = root counter
__device__ __align__(64) unsigned g_bar_flag[128];   // 8 replicas @ stride 16
__device__ __align__(64) unsigned g_bar_dead[16];    // [0] = timeout flag

DEVI ushort_t f2b(float f) {                // float -> bf16 bits, RNE
  union { float f; uint32_t u; } c; c.f = f;
  uint32_t u = c.u + 0x7fffu + ((c.u >> 16) & 1u);
  return (ushort_t)(u >> 16);
}
DEVI float b2f(ushort_t b) {
  union { uint32_t u; float f; } c; c.u = ((uint32_t)b) << 16; return c.f;
}
DEVI float sigm(float x) { return 1.f / (1.f + __expf(-x)); }

DEVI float4v mfma16(short8 a, short8 b, float4v c) {
  return __builtin_amdgcn_mfma_f32_16x16x32_bf16(a, b, c, 0, 0, 0);
}

// ---- coherent (LLC-routed) access helpers: compiler-generated sc0 sc1 -----
DEVI u64_t ld_sc8(const void* p) {
  return __hip_atomic_load((const u64_t*)p, __ATOMIC_RELAXED,
                           __HIP_MEMORY_SCOPE_SYSTEM);
}
DEVI float ld_scf(const float* p) {
  return __hip_atomic_load(p, __ATOMIC_RELAXED, __HIP_MEMORY_SCOPE_SYSTEM);
}
DEVI void st_scf(float* p, float v) {
  __hip_atomic_store(p, v, __ATOMIC_RELAXED, __HIP_MEMORY_SCOPE_SYSTEM);
}
DEVI void st_scu(unsigned* p, unsigned v) {
  __hip_atomic_store(p, v, __ATOMIC_RELAXED, __HIP_MEMORY_SCOPE_SYSTEM);
}

// A [32 x 1024] bf16 row-major via chunked sc loads; B pre-swizzled (L2-hot).
DEVI float4v gemm_sc(const ushort_t* Ab, const ushort_t* Bw,
                     int ntile, int mu, int lane) {
  float4v acc = {0.f, 0.f, 0.f, 0.f};
  const ushort_t* a = Ab + (size_t)(mu * 16 + (lane & 15)) * 1024 + ((lane >> 4) << 3);
  const ushort_t* b = Bw + ((size_t)ntile * 32 * 64 + lane) * 8;
  for (int c = 0; c < 4; ++c) {
    u64_t lo[8], hi[8];
#pragma unroll
    for (int j = 0; j < 8; ++j) {
      lo[j] = ld_sc8(a + (c * 8 + j) * 32);
      hi[j] = ld_sc8(a + (c * 8 + j) * 32 + 4);
    }
#pragma unroll
    for (int j = 0; j < 8; ++j) {
      union { u64_t u[2]; short8 s; } cv; cv.u[0] = lo[j]; cv.u[1] = hi[j];
      acc = mfma16(cv.s, *(const short8*)(b + (size_t)(c * 8 + j) * 512), acc);
    }
  }
  return acc;
}

// E gemm: K=2048, A = [h1b bf16 (sc) | ctx*inv f32->bf16 on the fly (sc)]
DEVI float4v gemm_scE(const ushort_t* h1b, const float* ctxn, const float* sden,
                      const ushort_t* Bw, int ntile, int mu, int lane) {
  float4v acc = {0.f, 0.f, 0.f, 0.f};
  const int m = mu * 16 + (lane & 15), ko = (lane >> 4) << 3;
  const ushort_t* a0 = h1b + (size_t)m * 1024 + ko;
  const float* a1 = ctxn + (size_t)m * 1024 + ko;
  const float den = ld_scf(&sden[m]);
  const float inv = (den > 1e-35f) ? (1.f / den) : 0.f;
  const ushort_t* b = Bw + ((size_t)ntile * 64 * 64 + lane) * 8;
  for (int c = 0; c < 4; ++c) {
    u64_t lo[8], hi[8];
#pragma unroll
    for (int j = 0; j < 8; ++j) {
      lo[j] = ld_sc8(a0 + (c * 8 + j) * 32);
      hi[j] = ld_sc8(a0 + (c * 8 + j) * 32 + 4);
    }
#pragma unroll
    for (int j = 0; j < 8; ++j) {
      union { u64_t u[2]; short8 s; } cv; cv.u[0] = lo[j]; cv.u[1] = hi[j];
      acc = mfma16(cv.s, *(const short8*)(b + (size_t)(c * 8 + j) * 512), acc);
    }
  }
  for (int c = 0; c < 8; ++c) {       // 32 kbs in chunks of 4
    u64_t t[16];
#pragma unroll
    for (int j = 0; j < 4; ++j)
#pragma unroll
      for (int q = 0; q < 4; ++q)
        t[j * 4 + q] = ld_sc8(a1 + (c * 4 + j) * 32 + q * 2);
#pragma unroll
    for (int j = 0; j < 4; ++j) {
      short8 av;
#pragma unroll
      for (int q = 0; q < 4; ++q) {
        union { u64_t u; float f[2]; } w; w.u = t[j * 4 + q];
        av[q * 2]     = (short)f2b(w.f[0] * inv);
        av[q * 2 + 1] = (short)f2b(w.f[1] * inv);
      }
      acc = mfma16(av, *(const short8*)(b + (size_t)(32 + c * 4 + j) * 512), acc);
    }
  }
  return acc;
}

// scatter C-fragment into LDS: sh[q*256 + m*16 + n]
DEVI void put_tile(float* sh, int q, int lane, float4v a) {
  const int base = q * 256 + (lane & 15);
#pragma unroll
  for (int i = 0; i < 4; ++i) sh[base + ((lane >> 4) * 4 + i) * 16] = a[i];
}

// ---------------------------------------------------------------------------
// Device barrier (v3-proven). No cache fences: all cross-WG data LLC-routed;
// __syncthreads() drains vmcnt per wave. Two-level arrival, bounded spin.
// ---------------------------------------------------------------------------
DEVI void gbar(unsigned idx, int tid, int wg) {
  __syncthreads();
  if (tid == 0) {
    if (__hip_atomic_load(&g_bar_dead[0], __ATOMIC_RELAXED,
                          __HIP_MEMORY_SCOPE_AGENT) == 0u) {
      const unsigned leaf = (unsigned)(wg & 7);
      const unsigned old = __hip_atomic_fetch_add(&g_bar_leaf[leaf * 16], 1u,
                             __ATOMIC_RELAXED, __HIP_MEMORY_SCOPE_AGENT);
      if (old == idx * 32u - 1u) {
        const unsigned o2 = __hip_atomic_fetch_add(&g_bar_root[0], 1u,
                              __ATOMIC_RELAXED, __HIP_MEMORY_SCOPE_AGENT);
        if (o2 == idx * 8u - 1u) {
#pragma unroll
          for (int r = 0; r < 8; ++r)
            __hip_atomic_store(&g_bar_flag[r * 16], idx,
                               __ATOMIC_RELAXED, __HIP_MEMORY_SCOPE_AGENT);
        }
      }
      const unsigned* fp = &g_bar_flag[leaf * 16];
      unsigned spins = 0;
      while (__hip_atomic_load(fp, __ATOMIC_RELAXED,
                               __HIP_MEMORY_SCOPE_AGENT) < idx) {
        __builtin_amdgcn_s_sleep(2);
        if (++spins > (1u << 22)) {
          __hip_atomic_store(&g_bar_dead[0], 1u,
                             __ATOMIC_RELAXED, __HIP_MEMORY_SCOPE_AGENT);
          break;
        }
      }
    }
  }
  __syncthreads();
}

// ---------------------------------------------------------------------------
// Prologue: WF = W_ih0 @ Wp  (fp32, [3072 x 1024])
// ---------------------------------------------------------------------------
__global__ void k_wf(const float* __restrict__ Wih0, const float* __restrict__ Wp) {
  __shared__ __align__(16) float As[32][128];
  __shared__ __align__(16) float Bs[128][64];
  const int tid = threadIdx.x;
  const int nt = blockIdx.x >> 4, kt = blockIdx.x & 15;
  const int n0 = nt * 32, k0 = kt * 64;
  {
    const int r = tid >> 3, c0 = (tid & 7) * 16;
    for (int i = 0; i < 16; i += 4)
      *(float4v*)&As[r][c0 + i] = *(const float4v*)&Wih0[(size_t)(n0 + r) * 128 + c0 + i];
  }
  {
    const int r = tid >> 1, c0 = (tid & 1) * 32;
    for (int i = 0; i < 32; i += 4)
      *(float4v*)&Bs[r][c0 + i] = *(const float4v*)&Wp[(size_t)r * 1024 + k0 + c0 + i];
  }
  __syncthreads();
  const int rn = tid >> 3, kq = (tid & 7) * 8;
  float acc[8] = {0.f, 0.f, 0.f, 0.f, 0.f, 0.f, 0.f, 0.f};
  for (int m = 0; m < 128; ++m) {
    const float a = As[rn][m];
#pragma unroll
    for (int j = 0; j < 8; ++j) acc[j] += a * Bs[m][kq + j];
  }
  float* dst = g_wf + (size_t)(n0 + rn) * 1024 + k0 + kq;
#pragma unroll
  for (int j = 0; j < 8; ++j) dst[j] = acc[j];
}

// Prologue: enc fp32 -> bf16 (same [32][512][1024] layout).
__global__ void k_encb(const float* __restrict__ enc) {
  const size_t i = ((size_t)blockIdx.x * 256 + threadIdx.x) * 8;
  if (i >= 16777216) return;
  float4v a = *(const float4v*)(enc + i);
  float4v b = *(const float4v*)(enc + i + 4);
  short8 r;
#pragma unroll
  for (int j = 0; j < 4; ++j) { r[j] = (short)f2b(a[j]); r[4 + j] = (short)f2b(b[j]); }
  *(short8*)(g_encb + i) = r;
}

// ---------------------------------------------------------------------------
// Prologue: round fp32 weights to bf16 and repack into B-fragment order.
// lane L holds B[k = kb*32 + (L>>4)*8 + i][n = ntile*16 + (L&15)]
// ---------------------------------------------------------------------------
__global__ void k_swz(const float* __restrict__ W1, const float* __restrict__ W2,
                      const float* __restrict__ W3, const float* __restrict__ WA,
                      const float* __restrict__ WC) {
  long fid = (long)blockIdx.x * 256 + threadIdx.x;
  if (fid >= 1966080) return;
  const float* src; int N, K; long base, local; bool tr = false;
  if      (fid < 393216)  { src = g_wf; N = 3072; K = 1024; base = SB_WF;  local = fid; }
  else if (fid < 786432)  { src = W1;   N = 3072; K = 1024; base = SB_IH1; local = fid - 393216; }
  else if (fid < 1179648) { src = W2;   N = 3072; K = 1024; base = SB_HH0; local = fid - 786432; }
  else if (fid < 1572864) { src = W3;   N = 3072; K = 1024; base = SB_HH1; local = fid - 1179648; }
  else if (fid < 1703936) { src = WA;   N = 1024; K = 1024; base = SB_AT;  local = fid - 1572864; tr = true; }
  else                    { src = WC;   N = 1024; K = 2048; base = SB_WC;  local = fid - 1703936; }
  const int L = (int)(local & 63);
  long rest = local >> 6;
  const int KB = K >> 5;
  const int kb = (int)(rest % KB);
  const int nt = (int)(rest / KB);
  const int n  = nt * 16 + (L & 15);
  const int k0 = kb * 32 + ((L >> 4) << 3);
  short8 r;
#pragma unroll
  for (int i = 0; i < 8; ++i) {
    float f = tr ? src[(size_t)(k0 + i) * N + n] : src[(size_t)n * K + (k0 + i)];
    r[i] = (short)f2b(f);
  }
  *(short8*)(g_sw + base + local * 8) = r;
}

// Prologue: init states, mask output, fused bias b0f, barrier reset.
__global__ void k_init(const float* __restrict__ ehid, const int* __restrict__ lens,
                       const float* __restrict__ Wih0, const float* __restrict__ bp,
                       const float* __restrict__ bih0,
                       float* __restrict__ out, int out_size) {
  int i = blockIdx.x * 256 + threadIdx.x;
  if (i == 0) {
#pragma unroll
    for (int r = 0; r < 8; ++r) {
      g_bar_leaf[r * 16] = 0u;
      g_bar_flag[r * 16] = 0u;
    }
    g_bar_root[0] = 0u;
    g_bar_dead[0] = 0u;
  }
  if (i < 32768) { float v = ehid[i]; g_h0f[i] = v; g_h0b[i] = f2b(v); }
  else if (i < 65536) {
    int j = i - 32768; float v = ehid[32768 + j];
    g_h1f[j] = v; g_h1b[j] = f2b(v);
  } else if (i < 78336) {
    int mi = i - 65536; int b = mi / 400, tt = mi % 400;
    int idx = 1651200 + mi;
    if (idx < out_size) out[idx] = (tt > lens[b]) ? 1.0f : 0.0f;
  } else if (i < 81408) {
    int n = i - 78336;
    float s = bih0[n];
    const float* wr = Wih0 + (size_t)n * 128;
    for (int m = 0; m < 128; ++m) s += bp[m] * wr[m];
    g_b0f[n] = s;
  }
}

// Prologue: gh0/gh1 for step 0 (plain; kernel boundary publishes).
DEVI float4v gemm_plain(const ushort_t* Ab, const ushort_t* Bw,
                        int ntile, int mu, int lane) {
  float4v acc = {0.f, 0.f, 0.f, 0.f};
  const ushort_t* a = Ab + (size_t)(mu * 16 + (lane & 15)) * 1024 + ((lane >> 4) << 3);
  const ushort_t* b = Bw + ((size_t)ntile * 32 * 64 + lane) * 8;
  for (int kb = 0; kb < 32; ++kb) {
    short8 av = *(const short8*)(a + kb * 32);
    acc = mfma16(av, *(const short8*)(b + (size_t)kb * 512), acc);
  }
  return acc;
}

__global__ void k_pre(const float* __restrict__ b_hh0, const float* __restrict__ b_hh1) {
  const int wg = blockIdx.x, tid = threadIdx.x;
  const int lane = tid & 63, wv = tid >> 6;
  __shared__ __align__(16) float sh[1536];
  const int qa = (wv < 2) ? wv * 2 : wv + 2;
  const int qb = (wv < 2) ? wv * 2 + 1 : -1;
  const ushort_t* Ab = (wg < 64) ? g_h0b : g_h1b;
  const ushort_t* Bw = g_sw + ((wg < 64) ? SB_HH0 : SB_HH1);
  const float* bhh = (wg < 64) ? b_hh0 : b_hh1;
  float* ghb = (wg < 64) ? g_gh0 : g_gh1;
  const int w16 = wg & 63;
  { int g = qa >> 1, mu = qa & 1;
    put_tile(sh, qa, lane, gemm_plain(Ab, Bw, g * 64 + w16, mu, lane)); }
  if (qb >= 0) { int g = qb >> 1, mu = qb & 1;
    put_tile(sh, qb, lane, gemm_plain(Ab, Bw, g * 64 + w16, mu, lane)); }
  __syncthreads();
  const int jl = tid & 15, mr = tid >> 4, jg = w16 * 16 + jl;
#pragma unroll
  for (int mu = 0; mu < 2; ++mu) {
    const int b = mu * 16 + mr;
#pragma unroll
    for (int g = 0; g < 3; ++g)
      ghb[b * 3072 + g * 1024 + jg] = sh[(g * 2 + mu) * 256 + tid] + bhh[g * 1024 + jg];
  }
}

// ---------------------------------------------------------------------------
// Phase A: GRU0 (WGs 0..63); mel writers t-1 (64..127); gate writer (128);
// zero ctx/den accumulators (129..136).
// ---------------------------------------------------------------------------
DEVI void phaseA(int t, int wg, int tid,
                 const float* __restrict__ b_ih0, const float* __restrict__ bp,
                 const float* __restrict__ Wp, const float* __restrict__ Wg,
                 const float* __restrict__ bg, const int* __restrict__ lens,
                 float* __restrict__ out, int out_size, float* sh) {
  const int lane = tid & 63, wv = tid >> 6;
  if (wg < 64) {
    if (t >= TM) return;
    const int qa = (wv < 2) ? wv * 2 : wv + 2;
    const int qb = (wv < 2) ? wv * 2 + 1 : -1;
    const ushort_t* SW = g_sw + SB_WF;
    float4v acc;
    { int g = qa >> 1, mu = qa & 1;
      acc = (t > 0) ? gemm_sc(g_cob, SW, g * 64 + wg, mu, lane)
                    : float4v{0.f, 0.f, 0.f, 0.f};
      put_tile(sh, qa, lane, acc); }
    if (qb >= 0) { int g = qb >> 1, mu = qb & 1;
      acc = (t > 0) ? gemm_sc(g_cob, SW, g * 64 + wg, mu, lane)
                    : float4v{0.f, 0.f, 0.f, 0.f};
      put_tile(sh, qb, lane, acc); }
    __syncthreads();
    const int jl = tid & 15, mr = tid >> 4, jg = wg * 16 + jl;
    const float* bs = (t > 0) ? g_b0f : b_ih0;   // t=0: dec_in = 0 -> plain b_ih0
    const float bir = bs[jg], biz = bs[1024 + jg], bin = bs[2048 + jg];
#pragma unroll
    for (int mu = 0; mu < 2; ++mu) {
      const int b = mu * 16 + mr;
      const float g0 = ld_scf(&g_gh0[b * 3072 + jg]);
      const float g1 = ld_scf(&g_gh0[b * 3072 + 1024 + jg]);
      const float g2 = ld_scf(&g_gh0[b * 3072 + 2048 + jg]);
      float gr = sh[mu * 256 + tid]       + bir + g0;
      float gz = sh[(2 + mu) * 256 + tid] + biz + g1;
      float gn = sh[(4 + mu) * 256 + tid] + bin;
      float r = sigm(gr), z = sigm(gz);
      float nn = tanhf(gn + r * g2);
      float h = (1.f - z) * nn + z * g_h0f[b * 1024 + jg];
      g_h0f[b * 1024 + jg] = h;                       // WG-local, plain
      ushort_t hb = f2b(h);
      ushort_t hb1 = (ushort_t)__shfl_down((int)hb, 1, 64);
      if (!(jl & 1))
        st_scu((unsigned*)&g_h0b[b * 1024 + jg],
               (unsigned)hb | ((unsigned)hb1 << 16));
    }
  } else if (wg < 128) {
    if (t == 0) return;
    const int idx = wg - 64, b = idx & 31, mh = idx >> 5;
    { union { u64_t u; float f[2]; } a, b2;
      a.u  = ld_sc8(g_cof + b * 1024 + tid * 4);
      b2.u = ld_sc8(g_cof + b * 1024 + tid * 4 + 2);
      sh[tid * 4]     = a.f[0];  sh[tid * 4 + 1] = a.f[1];
      sh[tid * 4 + 2] = b2.f[0]; sh[tid * 4 + 3] = b2.f[1]; }
    __syncthreads();
    const int m = mh * 64 + (tid >> 2), q = tid & 3;
    const float* cop = sh + q * 256;
    const float* wpp = Wp + (size_t)m * 1024 + q * 256;
    float s = 0.f;
#pragma unroll 8
    for (int k = 0; k < 256; k += 4) {
      float4v cv = *(const float4v*)(cop + k);
      float4v wv4 = *(const float4v*)(wpp + k);
      s += cv[0] * wv4[0] + cv[1] * wv4[1] + cv[2] * wv4[2] + cv[3] * wv4[3];
    }
    s += __shfl_xor(s, 1, 64);
    s += __shfl_xor(s, 2, 64);
    if (q == 0) {
      const bool mk = (t - 1) > lens[b];
      const float v = mk ? 0.f : (s + bp[m]);
      const int oidx = b * 51200 + (t - 1) * 128 + m;
      if (oidx < out_size) out[oidx] = v;
    }
  } else if (wg == 128) {
    if (t == 0) return;
    const int b = tid >> 3, seg = tid & 7;
    const float* cop = g_cof + b * 1024 + seg * 128;
    const float* wgp = Wg + seg * 128;
    float s = 0.f;
#pragma unroll
    for (int j = 0; j < 64; ++j) {
      union { u64_t u; float f[2]; } cv; cv.u = ld_sc8(cop + j * 2);
      s += cv.f[0] * wgp[j * 2] + cv.f[1] * wgp[j * 2 + 1];
    }
    for (int off = 1; off < 8; off <<= 1) s += __shfl_xor(s, off, 64);
    if (seg == 0) {
      const bool mk = (t - 1) > lens[b];
      const float g = mk ? 1000.f : (s + bg[0]);
      const int oidx = 1638400 + b * 400 + (t - 1);
      if (oidx < out_size) out[oidx] = g;
    }
  } else if (wg >= 129 && wg < 137) {
    const int z0 = (wg - 129) * 256 + tid;    // 2048 threads over 32768 floats
#pragma unroll
    for (int r4 = 0; r4 < 16; ++r4)
      st_scf(&g_ctxn[z0 + r4 * 2048], 0.f);
    if (wg == 129 && tid < 32) st_scf(&g_sden[tid], 0.f);
  }
}

// Phase B: GRU1 (WGs 0..63); gh0' for next step (64..127). A = h0b (sc).
DEVI void phaseB(int wg, int tid, const float* __restrict__ b_ih1,
                 const float* __restrict__ b_hh0, float* sh) {
  if (wg >= 128) return;
  const int lane = tid & 63, wv = tid >> 6;
  const int qa = (wv < 2) ? wv * 2 : wv + 2;
  const int qb = (wv < 2) ? wv * 2 + 1 : -1;
  const bool lo = (wg < 64);
  const int w16 = wg & 63;
  const ushort_t* SW = g_sw + (lo ? SB_IH1 : SB_HH0);
  { int g = qa >> 1, mu = qa & 1;
    put_tile(sh, qa, lane, gemm_sc(g_h0b, SW, g * 64 + w16, mu, lane)); }
  if (qb >= 0) { int g = qb >> 1, mu = qb & 1;
    put_tile(sh, qb, lane, gemm_sc(g_h0b, SW, g * 64 + w16, mu, lane)); }
  __syncthreads();
  const int jl = tid & 15, mr = tid >> 4, jg = w16 * 16 + jl;
  if (lo) {
    const float bir = b_ih1[jg], biz = b_ih1[1024 + jg], bin = b_ih1[2048 + jg];
#pragma unroll
    for (int mu = 0; mu < 2; ++mu) {
      const int b = mu * 16 + mr;
      float gr = sh[mu * 256 + tid]       + bir + g_gh1[b * 3072 + jg];
      float gz = sh[(2 + mu) * 256 + tid] + biz + g_gh1[b * 3072 + 1024 + jg];
      float gn = sh[(4 + mu) * 256 + tid] + bin;
      float r = sigm(gr), z = sigm(gz);
      float nn = tanhf(gn + r * g_gh1[b * 3072 + 2048 + jg]);
      const float hold = ld_scf(&g_h1f[b * 1024 + jg]);
      float h = (1.f - z) * nn + z * hold;
      st_scf(&g_h1f[b * 1024 + jg], h);
      ushort_t hb = f2b(h);
      ushort_t hb1 = (ushort_t)__shfl_down((int)hb, 1, 64);
      if (!(jl & 1))
        st_scu((unsigned*)&g_h1b[b * 1024 + jg],
               (unsigned)hb | ((unsigned)hb1 << 16));
    }
  } else {
#pragma unroll
    for (int mu = 0; mu < 2; ++mu) {
      const int b = mu * 16 + mr;
#pragma unroll
      for (int g = 0; g < 3; ++g)
        st_scf(&g_gh0[b * 3072 + g * 1024 + jg],
               sh[(g * 2 + mu) * 256 + tid] + b_hh0[g * 1024 + jg]);
    }
  }
}

// Phase C: gh1' (WGs 0..63, plain: WG-local); u~ (64..127); c-dot (128).
DEVI void phaseC(int wg, int tid, const float* __restrict__ b_hh1,
                 const float* __restrict__ b_attn, float* sh) {
  const int lane = tid & 63, wv = tid >> 6;
  if (wg < 64) {
    const int qa = (wv < 2) ? wv * 2 : wv + 2;
    const int qb = (wv < 2) ? wv * 2 + 1 : -1;
    const ushort_t* SW = g_sw + SB_HH1;
    { int g = qa >> 1, mu = qa & 1;
      put_tile(sh, qa, lane, gemm_sc(g_h1b, SW, g * 64 + wg, mu, lane)); }
    if (qb >= 0) { int g = qb >> 1, mu = qb & 1;
      put_tile(sh, qb, lane, gemm_sc(g_h1b, SW, g * 64 + wg, mu, lane)); }
    __syncthreads();
    const int jl = tid & 15, mr = tid >> 4, jg = wg * 16 + jl;
#pragma unroll
    for (int mu = 0; mu < 2; ++mu) {
      const int b = mu * 16 + mr;
#pragma unroll
      for (int g = 0; g < 3; ++g)
        g_gh1[b * 3072 + g * 1024 + jg] = sh[(g * 2 + mu) * 256 + tid] + b_hh1[g * 1024 + jg];
    }
  } else if (wg < 128) {
    const int nt = wg - 64;
    if (wv < 2) put_tile(sh, wv, lane, gemm_sc(g_h1b, g_sw + SB_AT, nt, wv, lane));
    __syncthreads();
    const int nl = tid & 15, mr = tid >> 4, n = nt * 16 + nl;
    st_scf(&g_ubuf[mr * 1024 + n],        sh[tid]);
    st_scf(&g_ubuf[(16 + mr) * 1024 + n], sh[256 + tid]);
  } else if (wg == 128) {
    const int b = tid >> 3, seg = tid & 7;
    const float* hp = g_h1f + b * 1024 + seg * 128;
    const float* ba = b_attn + seg * 128;
    float s = 0.f;
#pragma unroll
    for (int j = 0; j < 64; ++j) {
      union { u64_t u; float f[2]; } hv; hv.u = ld_sc8(hp + j * 2);
      s += hv.f[0] * ba[j * 2] + hv.f[1] * ba[j * 2 + 1];
    }
    for (int off = 1; off < 8; off <<= 1) s += __shfl_xor(s, off, 64);
    if (seg == 0) st_scf(&g_cbuf[b], s);
  }
}

// ---------------------------------------------------------------------------
// Phase D: attention from LDS-resident bf16 enc. WG (b, slot) owns 64 enc
// timesteps in ldsE. Lane owns dims [lane*8, lane*8+8) and [512+lane*8, +8).
// ctx/den reduced cross-WG via f32 LLC atomics.
// ---------------------------------------------------------------------------
DEVI void phaseD(int wg, int tid, const ushort_t* ldsE, float* sh) {
  const int lane = tid & 63, wv = tid >> 6;
  const int b = wg >> 3;
  const float* ub = g_ubuf + b * 1024;
  float u0[8], u1[8];
  {
    union { u64_t u; float f[2]; } t;
#pragma unroll
    for (int j = 0; j < 4; ++j) {
      t.u = ld_sc8(ub + lane * 8 + j * 2);
      u0[j * 2] = t.f[0]; u0[j * 2 + 1] = t.f[1];
    }
#pragma unroll
    for (int j = 0; j < 4; ++j) {
      t.u = ld_sc8(ub + 512 + lane * 8 + j * 2);
      u1[j * 2] = t.f[0]; u1[j * 2 + 1] = t.f[1];
    }
  }
  const float cb = ld_scf(&g_cbuf[b]);
  float cx0[8] = {0.f, 0.f, 0.f, 0.f, 0.f, 0.f, 0.f, 0.f};
  float cx1[8] = {0.f, 0.f, 0.f, 0.f, 0.f, 0.f, 0.f, 0.f};
  float sw = 0.f;
  for (int it = 0; it < 16; ++it) {
    const int tl = wv * 16 + it;
    short8 e0 = *(const short8*)(ldsE + tl * 1024 + lane * 8);
    short8 e1 = *(const short8*)(ldsE + tl * 1024 + 512 + lane * 8);
    float ef0[8], ef1[8];
#pragma unroll
    for (int j = 0; j < 8; ++j) {
      ef0[j] = b2f((ushort_t)e0[j]);
      ef1[j] = b2f((ushort_t)e1[j]);
    }
    float s = 0.f;
#pragma unroll
    for (int j = 0; j < 8; ++j) s += u0[j] * ef0[j] + u1[j] * ef1[j];
    for (int off = 1; off < 64; off <<= 1) s += __shfl_xor(s, off, 64);
    float sc = fminf(fmaxf(s + cb, -70.f), 70.f);   // identity in legit regime
    const float p = __expf(sc);
    sw += p;
#pragma unroll
    for (int j = 0; j < 8; ++j) { cx0[j] += p * ef0[j]; cx1[j] += p * ef1[j]; }
  }
#pragma unroll
  for (int j = 0; j < 8; ++j) {
    sh[wv * 1024 + lane * 8 + j]       = cx0[j];
    sh[wv * 1024 + 512 + lane * 8 + j] = cx1[j];
  }
  if (lane == 0) sh[4096 + wv] = sw;
  __syncthreads();
  float4v t4 = {0.f, 0.f, 0.f, 0.f};
#pragma unroll
  for (int vv = 0; vv < 4; ++vv) t4 += *(const float4v*)&sh[vv * 1024 + tid * 4];
  float* dst = g_ctxn + b * 1024 + tid * 4;
#pragma unroll
  for (int c = 0; c < 4; ++c) unsafeAtomicAdd(dst + c, t4[c]);
  if (tid == 0)
    unsafeAtomicAdd(&g_sden[b], sh[4096] + sh[4097] + sh[4098] + sh[4099]);
}

// Phase E: co = tanh([h1|ctx]@Wc^T + bc) -> g_cof (fp32) + g_cob (bf16).
DEVI void phaseE(int wg, int tid, const float* __restrict__ bc, float* sh) {
  if (wg >= 64) return;
  const int lane = tid & 63, wv = tid >> 6;
  if (wv < 2)
    put_tile(sh, wv, lane, gemm_scE(g_h1b, g_ctxn, g_sden, g_sw + SB_WC, wg, wv, lane));
  __syncthreads();
  const int jl = tid & 15, mr = tid >> 4;
  const float bcv = bc[wg * 16 + jl];
#pragma unroll
  for (int mu = 0; mu < 2; ++mu) {
    const int b = mu * 16 + mr;
    const float v = tanhf(sh[mu * 256 + tid] + bcv);
    st_scf(&g_cof[b * 1024 + wg * 16 + jl], v);
    ushort_t hb = f2b(v);
    ushort_t hb1 = (ushort_t)__shfl_down((int)hb, 1, 64);
    if (!(jl & 1))
      st_scu((unsigned*)&g_cob[b * 1024 + wg * 16 + jl],
             (unsigned)hb | ((unsigned)hb1 << 16));
  }
}

// ---------------------------------------------------------------------------
// Persistent kernel: all 400 steps, 5 device-scope barriers per step.
// grid = 256 WGs x 256 thr (one per CU). Each WG parks its enc slice
// (64 timesteps x 1024 dims, bf16 = 128 KB) in LDS once at start.
// ---------------------------------------------------------------------------
__global__ void __launch_bounds__(256) k_run(
    const float* __restrict__ b_ih0, const float* __restrict__ b_ih1,
    const float* __restrict__ b_hh0, const float* __restrict__ b_hh1,
    const float* __restrict__ b_attn, const float* __restrict__ bc,
    const float* __restrict__ Wp, const float* __restrict__ bp,
    const float* __restrict__ Wg, const float* __restrict__ bg,
    const int* __restrict__ lens, float* __restrict__ out, int out_size) {
  __shared__ __align__(16) ushort_t ldsE[65536];   // 128 KB enc slice
  __shared__ __align__(16) float sh[4160];         // 16.6 KB tiles/partials
  const int wg = blockIdx.x, tid = threadIdx.x;
  {
    // Fill the full 128 KB: 256 threads x 32 chunks x 16 B.
    // Thread (row = tid>>2, q = tid&3) owns shorts [q*256, q*256+256) of its
    // row; 32 iterations of 8 shorts (16 B) each.
    const int b = wg >> 3, slot = wg & 7;
    const ushort_t* src = g_encb + ((size_t)(b * 512 + slot * 64)) * 1024;
    const int row = tid >> 2, q = tid & 3;
#pragma unroll
    for (int i = 0; i < 32; ++i)
      *(float4v*)((char*)ldsE + row * 2048 + q * 512 + i * 16)
        = *(const float4v*)(src + (size_t)row * 1024 + q * 256 + i * 8);
  }
  __syncthreads();
  unsigned bar = 0;
  for (int t = 0; t < TM; ++t) {
    phaseA(t, wg, tid, b_ih0, bp, Wp, Wg, bg, lens, out, out_size, sh);
    gbar(++bar, tid, wg);
    phaseB(wg, tid, b_ih1, b_hh0, sh);
    gbar(++bar, tid, wg);
    phaseC(wg, tid, b_hh1, b_attn, sh);
    gbar(++bar, tid, wg);
    phaseD(wg, tid, ldsE, sh);
    gbar(++bar, tid, wg);
    phaseE(wg, tid, bc, sh);
    gbar(++bar, tid, wg);
  }
  // epilogue: outputs for t = TM-1 (writer roles only)
  phaseA(TM, wg, tid, b_ih0, bp, Wp, Wg, bg, lens, out, out_size, sh);
}

extern "C" void kernel_launch(void* const* d_in, const int* in_sizes, int n_in,
                              void* d_out, int out_size, void* d_ws, size_t ws_size,
                              hipStream_t stream) {
  const float* ehid  = (const float*)d_in[0];
  const float* enc   = (const float*)d_in[1];
  const int*   lens  = (const int*)d_in[3];
  const float* W_attn= (const float*)d_in[4];
  const float* b_attn= (const float*)d_in[5];
  const float* W_ih0 = (const float*)d_in[6];
  const float* W_hh0 = (const float*)d_in[7];
  const float* b_ih0 = (const float*)d_in[8];
  const float* b_hh0 = (const float*)d_in[9];
  const float* W_ih1 = (const float*)d_in[10];
  const float* W_hh1 = (const float*)d_in[11];
  const float* b_ih1 = (const float*)d_in[12];
  const float* b_hh1 = (const float*)d_in[13];
  const float* Wc    = (const float*)d_in[14];
  const float* bc    = (const float*)d_in[15];
  const float* Wp    = (const float*)d_in[16];
  const float* bp    = (const float*)d_in[17];
  const float* Wg    = (const float*)d_in[18];
  const float* bg    = (const float*)d_in[19];
  float* out = (float*)d_out;

  k_wf  <<<1536, 256, 0, stream>>>(W_ih0, Wp);
  k_encb<<<8192, 256, 0, stream>>>(enc);
  k_swz <<<7680, 256, 0, stream>>>(W_ih1, W_hh0, W_hh1, W_attn, Wc);
  k_init<<<318, 256, 0, stream>>>(ehid, lens, W_ih0, bp, b_ih0, out, out_size);
  k_pre <<<128, 256, 0, stream>>>(b_hh0, b_hh1);
  k_run <<<NWG, 256, 0, stream>>>(b_ih0, b_ih1, b_hh0, b_hh1, b_attn, bc,
                                  Wp, bp, Wg, bg, lens, out, out_size);
}

// Round 6
// 21232.898 us; speedup vs baseline: 3.2515x; 2.4093x over previous
//
#include <hip/hip_runtime.h>
#include <stdint.h>
#include <stddef.h>

// ---------------------------------------------------------------------------
// Autoregressive decoder for MI355X (gfx950) — multi-launch, 4 kernels/step.
// Lesson from v1-v5 (persistent attempts): in-kernel phase boundaries cost
// ~25us (LLC-latency-bound low-MLP reads + barrier) vs ~9us for a kernel
// launch with L2-cached reloads. So: launch-based, but restructured from the
// 7-kernel anchor (25.4ms) to 4 kernels/step:
//   - WF = W_ih0@Wp fusion (+ b0f = b_ih0 + W_ih0@bp): GRU0 consumes co
//     directly -> k_mel gone.
//   - ctx/den reduced via device fp32 atomics (v5-proven) -> k_red gone.
//   - energy = enc@W_attn^T + b_attn precomputed ONCE (bf16, prologue GEMM):
//     scores = h1 . energy[b,t] -> per-step u~ GEMV + c-dot gone, k_s2b gone
//     (gh1' moves to k_s4's idle WGs 64..127).
// Per step: s1 (GRU0 + t-1 output writers + ctx zero) -> s2 (GRU1 + gh0')
//        -> s3 (attention from bf16 energy/enc, atomics) -> s4 (co + gh1').
// All per-step loads are plain (L2-cached); kernel boundaries = coherence.
// GEMVs via v_mfma_f32_16x16x32_bf16, weights pre-swizzled bf16, fp32 acc.
// softmax w/o max-sub, clamped +-70 (identity in legit regime).
// ---------------------------------------------------------------------------

#define TM 400

typedef unsigned short ushort_t;
typedef short  short8  __attribute__((ext_vector_type(8)));
typedef float  float4v __attribute__((ext_vector_type(4)));

#define DEVI static __device__ __forceinline__

// swizzled-weight segment bases (in shorts, within g_sw)
#define SB_WF   0
#define SB_IH1  3145728
#define SB_HH0  6291456
#define SB_HH1  9437184
#define SB_AT   12582912
#define SB_WC   13631488
#define SW_TOT  15728640

__device__ __align__(16) ushort_t g_sw[SW_TOT];      // bf16 weights (L2-hot)
__device__ __align__(16) float    g_wf[3145728];     // WF = W_ih0 @ Wp (fp32)
__device__ __align__(16) ushort_t g_encb[16777216];  // enc bf16 [32][512][1024]
__device__ __align__(16) ushort_t g_energy[16777216];// energy bf16 (incl b_attn)
__device__ __align__(16) ushort_t g_h0b[32768], g_h1b[32768];
__device__ __align__(16) float    g_h0f[32768], g_h1f[32768];
__device__ __align__(16) float    g_b0f[3072];
__device__ __align__(16) float    g_gh0[98304], g_gh1[98304];
__device__ __align__(16) float    g_ctxn[32768], g_sden[32];   // atomic accums
__device__ __align__(16) float    g_cof[32768];      // co fp32
__device__ __align__(16) ushort_t g_cob[32768];      // co bf16

DEVI ushort_t f2b(float f) {                // float -> bf16 bits, RNE
  union { float f; uint32_t u; } c; c.f = f;
  uint32_t u = c.u + 0x7fffu + ((c.u >> 16) & 1u);
  return (ushort_t)(u >> 16);
}
DEVI float b2f(ushort_t b) {
  union { uint32_t u; float f; } c; c.u = ((uint32_t)b) << 16; return c.f;
}
DEVI float sigm(float x) { return 1.f / (1.f + __expf(-x)); }

DEVI float4v mfma16(short8 a, short8 b, float4v c) {
  return __builtin_amdgcn_mfma_f32_16x16x32_bf16(a, b, c, 0, 0, 0);
}

// A: bf16 [32 x 1024] row-major (plain loads); B: pre-swizzled frags. K=1024.
DEVI float4v gemm_plain(const ushort_t* Ab, const ushort_t* Bw,
                        int ntile, int mu, int lane) {
  float4v acc = {0.f, 0.f, 0.f, 0.f};
  const ushort_t* a = Ab + (size_t)(mu * 16 + (lane & 15)) * 1024 + ((lane >> 4) << 3);
  const ushort_t* b = Bw + ((size_t)ntile * 32 * 64 + lane) * 8;
  for (int kb = 0; kb < 32; ++kb) {
    short8 av = *(const short8*)(a + kb * 32);
    acc = mfma16(av, *(const short8*)(b + (size_t)kb * 512), acc);
  }
  return acc;
}

// co gemm: K=2048, A = [h1 bf16 | ctx*inv f32->bf16 on the fly], plain loads.
DEVI float4v gemm_coE(const ushort_t* h1b, const float* ctxn, const float* sden,
                      const ushort_t* Bw, int ntile, int mu, int lane) {
  float4v acc = {0.f, 0.f, 0.f, 0.f};
  const int m = mu * 16 + (lane & 15), ko = (lane >> 4) << 3;
  const ushort_t* a0 = h1b + (size_t)m * 1024 + ko;
  const float* a1 = ctxn + (size_t)m * 1024 + ko;
  const float den = sden[m];
  const float inv = (den > 1e-35f) ? (1.f / den) : 0.f;
  const ushort_t* b = Bw + ((size_t)ntile * 64 * 64 + lane) * 8;
  for (int kb = 0; kb < 32; ++kb)
    acc = mfma16(*(const short8*)(a0 + kb * 32),
                 *(const short8*)(b + (size_t)kb * 512), acc);
  for (int kb = 32; kb < 64; ++kb) {
    float4v w0 = *(const float4v*)(a1 + (kb - 32) * 32);
    float4v w1 = *(const float4v*)(a1 + (kb - 32) * 32 + 4);
    short8 av;
#pragma unroll
    for (int j = 0; j < 4; ++j) {
      av[j]     = (short)f2b(w0[j] * inv);
      av[4 + j] = (short)f2b(w1[j] * inv);
    }
    acc = mfma16(av, *(const short8*)(b + (size_t)kb * 512), acc);
  }
  return acc;
}

// scatter C-fragment into LDS: sh[q*256 + m*16 + n]
DEVI void put_tile(float* sh, int q, int lane, float4v a) {
  const int base = q * 256 + (lane & 15);
#pragma unroll
  for (int i = 0; i < 4; ++i) sh[base + ((lane >> 4) * 4 + i) * 16] = a[i];
}

// ---------------------------------------------------------------------------
// Prologue: WF = W_ih0 @ Wp  (fp32, [3072 x 1024])
// ---------------------------------------------------------------------------
__global__ void k_wf(const float* __restrict__ Wih0, const float* __restrict__ Wp) {
  __shared__ __align__(16) float As[32][128];
  __shared__ __align__(16) float Bs[128][64];
  const int tid = threadIdx.x;
  const int nt = blockIdx.x >> 4, kt = blockIdx.x & 15;
  const int n0 = nt * 32, k0 = kt * 64;
  {
    const int r = tid >> 3, c0 = (tid & 7) * 16;
    for (int i = 0; i < 16; i += 4)
      *(float4v*)&As[r][c0 + i] = *(const float4v*)&Wih0[(size_t)(n0 + r) * 128 + c0 + i];
  }
  {
    const int r = tid >> 1, c0 = (tid & 1) * 32;
    for (int i = 0; i < 32; i += 4)
      *(float4v*)&Bs[r][c0 + i] = *(const float4v*)&Wp[(size_t)r * 1024 + k0 + c0 + i];
  }
  __syncthreads();
  const int rn = tid >> 3, kq = (tid & 7) * 8;
  float acc[8] = {0.f, 0.f, 0.f, 0.f, 0.f, 0.f, 0.f, 0.f};
  for (int m = 0; m < 128; ++m) {
    const float a = As[rn][m];
#pragma unroll
    for (int j = 0; j < 8; ++j) acc[j] += a * Bs[m][kq + j];
  }
  float* dst = g_wf + (size_t)(n0 + rn) * 1024 + k0 + kq;
#pragma unroll
  for (int j = 0; j < 8; ++j) dst[j] = acc[j];
}

// Prologue: enc fp32 -> bf16 (same [32][512][1024] layout).
__global__ void k_encb(const float* __restrict__ enc) {
  const size_t i = ((size_t)blockIdx.x * 256 + threadIdx.x) * 8;
  if (i >= 16777216) return;
  float4v a = *(const float4v*)(enc + i);
  float4v b = *(const float4v*)(enc + i + 4);
  short8 r;
#pragma unroll
  for (int j = 0; j < 4; ++j) { r[j] = (short)f2b(a[j]); r[4 + j] = (short)f2b(b[j]); }
  *(short8*)(g_encb + i) = r;
}

// ---------------------------------------------------------------------------
// Prologue: round fp32 weights to bf16 and repack into B-fragment order.
// lane L holds B[k = kb*32 + (L>>4)*8 + i][n = ntile*16 + (L&15)]
// WA is packed NON-transposed here: B[k][n] = W_attn[n][k], so that
// energy = enc @ W_attn^T comes out of the same gemm machinery.
// ---------------------------------------------------------------------------
__global__ void k_swz(const float* __restrict__ W1, const float* __restrict__ W2,
                      const float* __restrict__ W3, const float* __restrict__ WA,
                      const float* __restrict__ WC) {
  long fid = (long)blockIdx.x * 256 + threadIdx.x;
  if (fid >= 1966080) return;
  const float* src; int N, K; long base, local;
  if      (fid < 393216)  { src = g_wf; N = 3072; K = 1024; base = SB_WF;  local = fid; }
  else if (fid < 786432)  { src = W1;   N = 3072; K = 1024; base = SB_IH1; local = fid - 393216; }
  else if (fid < 1179648) { src = W2;   N = 3072; K = 1024; base = SB_HH0; local = fid - 786432; }
  else if (fid < 1572864) { src = W3;   N = 3072; K = 1024; base = SB_HH1; local = fid - 1179648; }
  else if (fid < 1703936) { src = WA;   N = 1024; K = 1024; base = SB_AT;  local = fid - 1572864; }
  else                    { src = WC;   N = 1024; K = 2048; base = SB_WC;  local = fid - 1703936; }
  const int L = (int)(local & 63);
  long rest = local >> 6;
  const int KB = K >> 5;
  const int kb = (int)(rest % KB);
  const int nt = (int)(rest / KB);
  const int n  = nt * 16 + (L & 15);
  const int k0 = kb * 32 + ((L >> 4) << 3);
  short8 r;
#pragma unroll
  for (int i = 0; i < 8; ++i)
    r[i] = (short)f2b(src[(size_t)n * K + (k0 + i)]);
  *(short8*)(g_sw + base + local * 8) = r;
}

// ---------------------------------------------------------------------------
// Prologue: energy = enc @ W_attn^T + b_attn -> bf16 [32][512][1024].
// Grid 512: WG rt handles rows [rt*32, rt*32+32); wave wv handles 16 ntiles.
// ---------------------------------------------------------------------------
__global__ void k_energy(const float* __restrict__ b_attn) {
  __shared__ __align__(16) float sh[2048];
  const int tid = threadIdx.x, lane = tid & 63, wv = tid >> 6;
  const int rt = blockIdx.x;
  const ushort_t* Ab = g_encb + (size_t)rt * 32 * 1024;
  float* shw = sh + wv * 512;
  for (int i = 0; i < 16; ++i) {
    const int nt = wv * 16 + i;
    put_tile(shw, 0, lane, gemm_plain(Ab, g_sw + SB_AT, nt, 0, lane));
    put_tile(shw, 1, lane, gemm_plain(Ab, g_sw + SB_AT, nt, 1, lane));
    __syncthreads();
    const int row = lane >> 1, cf = (lane & 1) * 8;
    const int q = row >> 4, r = row & 15;
    short8 o;
#pragma unroll
    for (int j = 0; j < 8; ++j) {
      const int n = nt * 16 + cf + j;
      o[j] = (short)f2b(shw[q * 256 + r * 16 + cf + j] + b_attn[n]);
    }
    *(short8*)(g_energy + (size_t)(rt * 32 + row) * 1024 + nt * 16 + cf) = o;
    __syncthreads();
  }
}

// Prologue: init states, mask output, fused bias b0f.
__global__ void k_init(const float* __restrict__ ehid, const int* __restrict__ lens,
                       const float* __restrict__ Wih0, const float* __restrict__ bp,
                       const float* __restrict__ bih0,
                       float* __restrict__ out, int out_size) {
  int i = blockIdx.x * 256 + threadIdx.x;
  if (i < 32768) { float v = ehid[i]; g_h0f[i] = v; g_h0b[i] = f2b(v); }
  else if (i < 65536) {
    int j = i - 32768; float v = ehid[32768 + j];
    g_h1f[j] = v; g_h1b[j] = f2b(v);
  } else if (i < 78336) {
    int mi = i - 65536; int b = mi / 400, tt = mi % 400;
    int idx = 1651200 + mi;
    if (idx < out_size) out[idx] = (tt > lens[b]) ? 1.0f : 0.0f;
  } else if (i < 81408) {
    int n = i - 78336;
    float s = bih0[n];
    const float* wr = Wih0 + (size_t)n * 128;
    for (int m = 0; m < 128; ++m) s += bp[m] * wr[m];
    g_b0f[n] = s;
  }
}

// Prologue: gh0/gh1 for step 0 (h_init @ W_hh^T + b_hh).
__global__ void k_pre(const float* __restrict__ b_hh0, const float* __restrict__ b_hh1) {
  const int wg = blockIdx.x, tid = threadIdx.x;
  const int lane = tid & 63, wv = tid >> 6;
  __shared__ __align__(16) float sh[1536];
  const int qa = (wv < 2) ? wv * 2 : wv + 2;
  const int qb = (wv < 2) ? wv * 2 + 1 : -1;
  const ushort_t* Ab = (wg < 64) ? g_h0b : g_h1b;
  const ushort_t* Bw = g_sw + ((wg < 64) ? SB_HH0 : SB_HH1);
  const float* bhh = (wg < 64) ? b_hh0 : b_hh1;
  float* ghb = (wg < 64) ? g_gh0 : g_gh1;
  const int w16 = wg & 63;
  { int g = qa >> 1, mu = qa & 1;
    put_tile(sh, qa, lane, gemm_plain(Ab, Bw, g * 64 + w16, mu, lane)); }
  if (qb >= 0) { int g = qb >> 1, mu = qb & 1;
    put_tile(sh, qb, lane, gemm_plain(Ab, Bw, g * 64 + w16, mu, lane)); }
  __syncthreads();
  const int jl = tid & 15, mr = tid >> 4, jg = w16 * 16 + jl;
#pragma unroll
  for (int mu = 0; mu < 2; ++mu) {
    const int b = mu * 16 + mr;
#pragma unroll
    for (int g = 0; g < 3; ++g)
      ghb[b * 3072 + g * 1024 + jg] = sh[(g * 2 + mu) * 256 + tid] + bhh[g * 1024 + jg];
  }
}

// ---------------------------------------------------------------------------
// s1: GRU0 (WGs 0..63, A = co bf16, B = WF); mel writers t-1 (64..127);
// gate writer (128); zero ctx/den accumulators (129..136). Grid 137.
// ---------------------------------------------------------------------------
__global__ void k_s1(int t, const float* __restrict__ b_ih0, const float* __restrict__ bp,
                     const float* __restrict__ Wp, const float* __restrict__ Wg,
                     const float* __restrict__ bg, const int* __restrict__ lens,
                     float* __restrict__ out, int out_size) {
  const int wg = blockIdx.x, tid = threadIdx.x;
  const int lane = tid & 63, wv = tid >> 6;
  __shared__ __align__(16) float sh[1536];
  if (wg < 64) {
    if (t >= TM) return;
    const int qa = (wv < 2) ? wv * 2 : wv + 2;
    const int qb = (wv < 2) ? wv * 2 + 1 : -1;
    const ushort_t* SW = g_sw + SB_WF;
    float4v acc;
    { int g = qa >> 1, mu = qa & 1;
      acc = (t > 0) ? gemm_plain(g_cob, SW, g * 64 + wg, mu, lane)
                    : float4v{0.f, 0.f, 0.f, 0.f};
      put_tile(sh, qa, lane, acc); }
    if (qb >= 0) { int g = qb >> 1, mu = qb & 1;
      acc = (t > 0) ? gemm_plain(g_cob, SW, g * 64 + wg, mu, lane)
                    : float4v{0.f, 0.f, 0.f, 0.f};
      put_tile(sh, qb, lane, acc); }
    __syncthreads();
    const int jl = tid & 15, mr = tid >> 4, jg = wg * 16 + jl;
    const float* bs = (t > 0) ? g_b0f : b_ih0;   // t=0: dec_in = 0 -> plain b_ih0
    const float bir = bs[jg], biz = bs[1024 + jg], bin = bs[2048 + jg];
#pragma unroll
    for (int mu = 0; mu < 2; ++mu) {
      const int b = mu * 16 + mr;
      float gr = sh[mu * 256 + tid]       + bir + g_gh0[b * 3072 + jg];
      float gz = sh[(2 + mu) * 256 + tid] + biz + g_gh0[b * 3072 + 1024 + jg];
      float gn = sh[(4 + mu) * 256 + tid] + bin;
      float r = sigm(gr), z = sigm(gz);
      float nn = tanhf(gn + r * g_gh0[b * 3072 + 2048 + jg]);
      float h = (1.f - z) * nn + z * g_h0f[b * 1024 + jg];
      g_h0f[b * 1024 + jg] = h; g_h0b[b * 1024 + jg] = f2b(h);
    }
  } else if (wg < 128) {
    if (t == 0) return;
    const int idx = wg - 64, b = idx & 31, mh = idx >> 5;
    *(float4v*)&sh[tid * 4] = *(const float4v*)(g_cof + b * 1024 + tid * 4);
    __syncthreads();
    const int m = mh * 64 + (tid >> 2), q = tid & 3;
    const float* cop = sh + q * 256;
    const float* wpp = Wp + (size_t)m * 1024 + q * 256;
    float s = 0.f;
#pragma unroll 8
    for (int k = 0; k < 256; k += 4) {
      float4v cv = *(const float4v*)(cop + k);
      float4v wv4 = *(const float4v*)(wpp + k);
      s += cv[0] * wv4[0] + cv[1] * wv4[1] + cv[2] * wv4[2] + cv[3] * wv4[3];
    }
    s += __shfl_xor(s, 1, 64);
    s += __shfl_xor(s, 2, 64);
    if (q == 0) {
      const bool mk = (t - 1) > lens[b];
      const float v = mk ? 0.f : (s + bp[m]);
      const int oidx = b * 51200 + (t - 1) * 128 + m;
      if (oidx < out_size) out[oidx] = v;
    }
  } else if (wg == 128) {
    if (t == 0) return;
    const int b = tid >> 3, seg = tid & 7;
    const float* cop = g_cof + b * 1024 + seg * 128;
    const float* wgp = Wg + seg * 128;
    float s = 0.f;
#pragma unroll 8
    for (int k = 0; k < 128; k += 4) {
      float4v cv = *(const float4v*)(cop + k);
      float4v wv4 = *(const float4v*)(wgp + k);
      s += cv[0] * wv4[0] + cv[1] * wv4[1] + cv[2] * wv4[2] + cv[3] * wv4[3];
    }
    for (int o = 1; o < 8; o <<= 1) s += __shfl_xor(s, o, 64);
    if (seg == 0) {
      const bool mk = (t - 1) > lens[b];
      const float g = mk ? 1000.f : (s + bg[0]);
      const int oidx = 1638400 + b * 400 + (t - 1);
      if (oidx < out_size) out[oidx] = g;
    }
  } else {                      // wg 129..136: zero ctx/den for this step
    const int z0 = (wg - 129) * 256 + tid;
#pragma unroll
    for (int r4 = 0; r4 < 16; ++r4) g_ctxn[z0 + r4 * 2048] = 0.f;
    if (wg == 129 && tid < 32) g_sden[tid] = 0.f;
  }
}

// s2: GRU1 (WGs 0..63); gh0' for next step (64..127). Grid 128.
__global__ void k_s2(const float* __restrict__ b_ih1, const float* __restrict__ b_hh0) {
  const int wg = blockIdx.x, tid = threadIdx.x;
  const int lane = tid & 63, wv = tid >> 6;
  __shared__ __align__(16) float sh[1536];
  const int qa = (wv < 2) ? wv * 2 : wv + 2;
  const int qb = (wv < 2) ? wv * 2 + 1 : -1;
  const bool lo = (wg < 64);
  const int w16 = wg & 63;
  const ushort_t* SW = g_sw + (lo ? SB_IH1 : SB_HH0);
  { int g = qa >> 1, mu = qa & 1;
    put_tile(sh, qa, lane, gemm_plain(g_h0b, SW, g * 64 + w16, mu, lane)); }
  if (qb >= 0) { int g = qb >> 1, mu = qb & 1;
    put_tile(sh, qb, lane, gemm_plain(g_h0b, SW, g * 64 + w16, mu, lane)); }
  __syncthreads();
  const int jl = tid & 15, mr = tid >> 4, jg = w16 * 16 + jl;
  if (lo) {
    const float bir = b_ih1[jg], biz = b_ih1[1024 + jg], bin = b_ih1[2048 + jg];
#pragma unroll
    for (int mu = 0; mu < 2; ++mu) {
      const int b = mu * 16 + mr;
      float gr = sh[mu * 256 + tid]       + bir + g_gh1[b * 3072 + jg];
      float gz = sh[(2 + mu) * 256 + tid] + biz + g_gh1[b * 3072 + 1024 + jg];
      float gn = sh[(4 + mu) * 256 + tid] + bin;
      float r = sigm(gr), z = sigm(gz);
      float nn = tanhf(gn + r * g_gh1[b * 3072 + 2048 + jg]);
      float h = (1.f - z) * nn + z * g_h1f[b * 1024 + jg];
      g_h1f[b * 1024 + jg] = h; g_h1b[b * 1024 + jg] = f2b(h);
    }
  } else {
#pragma unroll
    for (int mu = 0; mu < 2; ++mu) {
      const int b = mu * 16 + mr;
#pragma unroll
      for (int g = 0; g < 3; ++g)
        g_gh0[b * 3072 + g * 1024 + jg] = sh[(g * 2 + mu) * 256 + tid] + b_hh0[g * 1024 + jg];
    }
  }
}

// ---------------------------------------------------------------------------
// s3: attention. WG (b, slot): 64 enc timesteps. scores = h1 . energy[b,t]
// (bias already folded into energy). ctx/den via device f32 atomics. Grid 256.
// ---------------------------------------------------------------------------
__global__ void k_s3() {
  __shared__ __align__(16) float sh[4160];
  const int wg = blockIdx.x, tid = threadIdx.x;
  const int lane = tid & 63, wv = tid >> 6;
  const int b = wg >> 3, slot = wg & 7;
  const float* hp = g_h1f + b * 1024;
  float u0[8], u1[8];
  {
    float4v a0 = *(const float4v*)(hp + lane * 8);
    float4v a1 = *(const float4v*)(hp + lane * 8 + 4);
    float4v b0 = *(const float4v*)(hp + 512 + lane * 8);
    float4v b1 = *(const float4v*)(hp + 512 + lane * 8 + 4);
#pragma unroll
    for (int j = 0; j < 4; ++j) {
      u0[j] = a0[j]; u0[4 + j] = a1[j];
      u1[j] = b0[j]; u1[4 + j] = b1[j];
    }
  }
  float cx0[8] = {0.f, 0.f, 0.f, 0.f, 0.f, 0.f, 0.f, 0.f};
  float cx1[8] = {0.f, 0.f, 0.f, 0.f, 0.f, 0.f, 0.f, 0.f};
  float sw = 0.f;
  const size_t base = ((size_t)(b * 512 + slot * 64 + wv * 16)) * 1024 + lane * 8;
  for (int it = 0; it < 16; ++it) {
    const size_t off = base + (size_t)it * 1024;
    short8 g0 = *(const short8*)(g_energy + off);
    short8 g1 = *(const short8*)(g_energy + off + 512);
    short8 e0 = *(const short8*)(g_encb + off);
    short8 e1 = *(const short8*)(g_encb + off + 512);
    float ef0[8], ef1[8];
    float s = 0.f;
#pragma unroll
    for (int j = 0; j < 8; ++j) {
      ef0[j] = b2f((ushort_t)e0[j]);
      ef1[j] = b2f((ushort_t)e1[j]);
      s += u0[j] * b2f((ushort_t)g0[j]) + u1[j] * b2f((ushort_t)g1[j]);
    }
    for (int o = 1; o < 64; o <<= 1) s += __shfl_xor(s, o, 64);
    const float sc = fminf(fmaxf(s, -70.f), 70.f);  // identity in legit regime
    const float p = __expf(sc);
    sw += p;
#pragma unroll
    for (int j = 0; j < 8; ++j) { cx0[j] += p * ef0[j]; cx1[j] += p * ef1[j]; }
  }
#pragma unroll
  for (int j = 0; j < 8; ++j) {
    sh[wv * 1024 + lane * 8 + j]       = cx0[j];
    sh[wv * 1024 + 512 + lane * 8 + j] = cx1[j];
  }
  if (lane == 0) sh[4096 + wv] = sw;
  __syncthreads();
  float4v t4 = {0.f, 0.f, 0.f, 0.f};
#pragma unroll
  for (int v = 0; v < 4; ++v) t4 += *(const float4v*)&sh[v * 1024 + tid * 4];
  float* dst = g_ctxn + b * 1024 + tid * 4;
#pragma unroll
  for (int c = 0; c < 4; ++c) unsafeAtomicAdd(dst + c, t4[c]);
  if (tid == 0)
    unsafeAtomicAdd(&g_sden[b], sh[4096] + sh[4097] + sh[4098] + sh[4099]);
}

// s4: co = tanh([h1|ctx]@Wc^T + bc) (WGs 0..63) + gh1' for next step
// (64..127). Grid 128.
__global__ void k_s4(const float* __restrict__ bc, const float* __restrict__ b_hh1) {
  const int wg = blockIdx.x, tid = threadIdx.x;
  const int lane = tid & 63, wv = tid >> 6;
  __shared__ __align__(16) float sh[1536];
  if (wg < 64) {
    if (wv < 2)
      put_tile(sh, wv, lane, gemm_coE(g_h1b, g_ctxn, g_sden, g_sw + SB_WC, wg, wv, lane));
    __syncthreads();
    const int jl = tid & 15, mr = tid >> 4;
    const float bcv = bc[wg * 16 + jl];
#pragma unroll
    for (int mu = 0; mu < 2; ++mu) {
      const int b = mu * 16 + mr;
      const float v = tanhf(sh[mu * 256 + tid] + bcv);
      g_cof[b * 1024 + wg * 16 + jl] = v;
      g_cob[b * 1024 + wg * 16 + jl] = f2b(v);
    }
  } else {
    const int w16 = wg - 64;
    const int qa = (wv < 2) ? wv * 2 : wv + 2;
    const int qb = (wv < 2) ? wv * 2 + 1 : -1;
    { int g = qa >> 1, mu = qa & 1;
      put_tile(sh, qa, lane, gemm_plain(g_h1b, g_sw + SB_HH1, g * 64 + w16, mu, lane)); }
    if (qb >= 0) { int g = qb >> 1, mu = qb & 1;
      put_tile(sh, qb, lane, gemm_plain(g_h1b, g_sw + SB_HH1, g * 64 + w16, mu, lane)); }
    __syncthreads();
    const int jl = tid & 15, mr = tid >> 4, jg = w16 * 16 + jl;
#pragma unroll
    for (int mu = 0; mu < 2; ++mu) {
      const int b = mu * 16 + mr;
#pragma unroll
      for (int g = 0; g < 3; ++g)
        g_gh1[b * 3072 + g * 1024 + jg] = sh[(g * 2 + mu) * 256 + tid] + b_hh1[g * 1024 + jg];
    }
  }
}

extern "C" void kernel_launch(void* const* d_in, const int* in_sizes, int n_in,
                              void* d_out, int out_size, void* d_ws, size_t ws_size,
                              hipStream_t stream) {
  const float* ehid  = (const float*)d_in[0];
  const float* enc   = (const float*)d_in[1];
  const int*   lens  = (const int*)d_in[3];
  const float* W_attn= (const float*)d_in[4];
  const float* b_attn= (const float*)d_in[5];
  const float* W_ih0 = (const float*)d_in[6];
  const float* W_hh0 = (const float*)d_in[7];
  const float* b_ih0 = (const float*)d_in[8];
  const float* b_hh0 = (const float*)d_in[9];
  const float* W_ih1 = (const float*)d_in[10];
  const float* W_hh1 = (const float*)d_in[11];
  const float* b_ih1 = (const float*)d_in[12];
  const float* b_hh1 = (const float*)d_in[13];
  const float* Wc    = (const float*)d_in[14];
  const float* bc    = (const float*)d_in[15];
  const float* Wp    = (const float*)d_in[16];
  const float* bp    = (const float*)d_in[17];
  const float* Wg    = (const float*)d_in[18];
  const float* bg    = (const float*)d_in[19];
  float* out = (float*)d_out;

  k_wf    <<<1536, 256, 0, stream>>>(W_ih0, Wp);
  k_encb  <<<8192, 256, 0, stream>>>(enc);
  k_swz   <<<7680, 256, 0, stream>>>(W_ih1, W_hh0, W_hh1, W_attn, Wc);
  k_energy<<<512,  256, 0, stream>>>(b_attn);
  k_init  <<<318,  256, 0, stream>>>(ehid, lens, W_ih0, bp, b_ih0, out, out_size);
  k_pre   <<<128,  256, 0, stream>>>(b_hh0, b_hh1);
  for (int t = 0; t < TM; ++t) {
    k_s1<<<137, 256, 0, stream>>>(t, b_ih0, bp, Wp, Wg, bg, lens, out, out_size);
    k_s2<<<128, 256, 0, stream>>>(b_ih1, b_hh0);
    k_s3<<<256, 256, 0, stream>>>();
    k_s4<<<128, 256, 0, stream>>>(bc, b_hh1);
  }
  k_s1<<<137, 256, 0, stream>>>(TM, b_ih0, bp, Wp, Wg, bg, lens, out, out_size);
}